// Round 3
// baseline (4791.698 us; speedup 1.0000x reference)
//
#include <hip/hip_runtime.h>
#include <hip/hip_bf16.h>
#include <math.h>

#define NB    16
#define NPC   4096        // points per cloud
#define MPC   1024        // clusters per cloud
#define PTOT  65536
#define NCLU  16384
#define KNN_  16
#define CIN   64
#define COUT_ 128
#define CAUX_ 32

// out offsets (float elements), outputs concatenated in reference return order
#define OFF_XOUT   0
#define OFF_SUBPOS (NCLU*COUT_)               // 2097152
#define OFF_SUBB   (OFF_SUBPOS + NCLU*3)      // 2146304
#define OFF_AUX    (OFF_SUBB + NCLU)          // 2162688
#define OFF_IDCL   (OFF_AUX + NCLU*CAUX_)     // 2686976

// ws offsets (bytes)
#define WS_H        0
#define WS_CENTERS  (PTOT*COUT_*4)            // 33554432  (h: P x 128 f32)
#define WS_NN       (WS_CENTERS + NCLU*16)    // centers: float4 per cluster
#define WS_STATS    (WS_NN + NCLU*KNN_*4)     // nn ids
#define WS_SS       (WS_STATS + 256*4)        // sum[128], sumsq[128]
#define WS_NEED     (WS_SS + 256*4)           // scale[128], shift[128]

// ---- DPP cross-lane helpers (VALU pipe, ~2-4cy vs ~50cy ds_permute) --------
// update_dpp(old, src, ctrl, row_mask, bank_mask, bound_ctrl=false):
// lanes with no valid source (or masked out) receive `old`.
#define DPP_SHR1   0x111
#define DPP_SHR2   0x112
#define DPP_SHR4   0x114
#define DPP_SHR8   0x118
#define DPP_BC15   0x142
#define DPP_BC31   0x143

template <int CTRL>
__device__ __forceinline__ float dpp_f(float x, float oldv) {
  return __int_as_float(__builtin_amdgcn_update_dpp(
      __float_as_int(oldv), __float_as_int(x), CTRL, 0xf, 0xf, false));
}
template <int CTRL>
__device__ __forceinline__ int dpp_i(int x, int oldv) {
  return __builtin_amdgcn_update_dpp(oldv, x, CTRL, 0xf, 0xf, false);
}

// ---------------- FPS: one block/cloud, 256 thr, DPP reduce, no global in loop
__global__ __launch_bounds__(256) void fps_kernel(const float* __restrict__ pos,
                                                  float4* __restrict__ centers,
                                                  float* __restrict__ out)
{
  #pragma clang fp contract(off)
  __shared__ float4 sA[2][4];     // per-wave candidate: (v, asfloat(idx), x, y)
  __shared__ float  sZ[2][4];     // z
  __shared__ float4 cst[MPC];     // per-step result: (x, y, z, asfloat(sel))
  __shared__ float4 s0;           // point-0 broadcast
  const int b    = blockIdx.x;
  const int t    = threadIdx.x;
  const int lane = t & 63;
  const int wid  = t >> 6;
  const float* pb = pos + (size_t)b * NPC * 3;

  // Each thread owns 16 consecutive points: in-cloud idx t*16..t*16+15.
  float px[16], py[16], pz[16], mind[16];
  {
    const float4* src = (const float4*)(pb + t * 48);
    float4 v[12];
    #pragma unroll
    for (int i = 0; i < 12; ++i) v[i] = src[i];
    const float* f = (const float*)v;
    #pragma unroll
    for (int j = 0; j < 16; ++j) { px[j] = f[3*j]; py[j] = f[3*j+1]; pz[j] = f[3*j+2]; }
  }
  if (t == 0) s0 = make_float4(px[0], py[0], pz[0], 0.0f);
  __syncthreads();
  const float x0 = s0.x, y0 = s0.y, z0 = s0.z;
  if (t == 0) cst[0] = make_float4(x0, y0, z0, __int_as_float(0));

  // initial distances to point 0 + local tree-argmax
  float bv; int bi; float bx, by, bz;
  {
    float d[16];
    #pragma unroll
    for (int j = 0; j < 16; ++j) {
      float dx = px[j]-x0, dy = py[j]-y0, dz = pz[j]-z0;
      d[j] = (dx*dx + dy*dy) + dz*dz;   // no-FMA: matches numpy rounding
      mind[j] = d[j];
    }
    float tv[8]; int ti[8];
    #pragma unroll
    for (int j = 0; j < 8; ++j) {       // pair (2j,2j+1): right wins only if strictly >
      bool c = d[2*j+1] > d[2*j];
      tv[j] = c ? d[2*j+1] : d[2*j]; ti[j] = c ? 2*j+1 : 2*j;
    }
    #pragma unroll
    for (int j = 0; j < 4; ++j) { bool c = tv[2*j+1] > tv[2*j];
      tv[j] = c ? tv[2*j+1] : tv[2*j]; ti[j] = c ? ti[2*j+1] : ti[2*j]; }
    #pragma unroll
    for (int j = 0; j < 2; ++j) { bool c = tv[2*j+1] > tv[2*j];
      tv[j] = c ? tv[2*j+1] : tv[2*j]; ti[j] = c ? ti[2*j+1] : ti[2*j]; }
    bool c = tv[1] > tv[0];
    bv = c ? tv[1] : tv[0]; bi = t*16 + (c ? ti[1] : ti[0]);
    bx = px[bi - t*16]; by = py[bi - t*16]; bz = pz[bi - t*16];
  }
  // NOTE: the bx/by/bz indexing above is runtime — replace with tree-carried coords:
  // (recomputed below properly in-loop; for step-1 entry we carry via tree too)
  // To avoid scratch, recompute coords by one more selection pass:
  {
    int jl = bi - t*16;
    float sx = px[0], sy = py[0], sz = pz[0];
    #pragma unroll
    for (int j = 1; j < 16; ++j) {
      bool c = (jl == j);
      sx = c ? px[j] : sx; sy = c ? py[j] : sy; sz = c ? pz[j] : sz;
    }
    bx = sx; by = sy; bz = sz;
  }

  for (int s = 1; s < MPC; ++s) {
    // ---- intra-wave DPP scan: max (v desc, idx asc), carrying coords ------
    float v = bv; int vi = bi; float cx = bx, cy = by, cz = bz;
    #define LEV(CTRL) { \
      float ov = dpp_f<CTRL>(v, -1.0f); \
      int   oi = dpp_i<CTRL>(vi, 0x7fffffff); \
      float ox = dpp_f<CTRL>(cx, 0.0f); \
      float oy = dpp_f<CTRL>(cy, 0.0f); \
      float oz = dpp_f<CTRL>(cz, 0.0f); \
      bool c = (ov > v) || (ov == v && oi < vi); \
      v = c ? ov : v; vi = c ? oi : vi; cx = c ? ox : cx; cy = c ? oy : cy; cz = c ? oz : cz; }
    LEV(DPP_SHR1) LEV(DPP_SHR2) LEV(DPP_SHR4) LEV(DPP_SHR8) LEV(DPP_BC15) LEV(DPP_BC31)
    #undef LEV
    const int p = s & 1;
    if (lane == 63) { sA[p][wid] = make_float4(v, __int_as_float(vi), cx, cy); sZ[p][wid] = cz; }
    __syncthreads();                         // lgkm-only drain: no global stores in loop
    float4 bb = sA[p][0]; float bzz = sZ[p][0];
    #pragma unroll
    for (int w = 1; w < 4; ++w) {
      float4 o = sA[p][w]; float oz2 = sZ[p][w];
      bool c = (o.x > bb.x) || (o.x == bb.x && __float_as_int(o.y) < __float_as_int(bb.y));
      if (c) { bb = o; bzz = oz2; }
    }
    const int   sel = __float_as_int(bb.y);
    const float sx = bb.z, sy = bb.w, sz2 = bzz;
    if (t == 0) cst[s] = make_float4(sx, sy, sz2, bb.y);
    // ---- distance update + local tree-argmax (carry coords through tree) --
    bv = -1.0f; bi = 0; bx = 0; by = 0; bz = 0;
    {
      float m[16];
      #pragma unroll
      for (int j = 0; j < 16; ++j) {
        float dx = px[j]-sx, dy = py[j]-sy, dz = pz[j]-sz2;
        float d = (dx*dx + dy*dy) + dz*dz;
        m[j] = fminf(mind[j], d);
        mind[j] = m[j];
      }
      float tv[8]; int tj[8]; float txc[8], tyc[8], tzc[8];
      #pragma unroll
      for (int j = 0; j < 8; ++j) {
        bool c = m[2*j+1] > m[2*j];
        tv[j] = c ? m[2*j+1] : m[2*j];
        tj[j] = c ? 2*j+1 : 2*j;
        txc[j] = c ? px[2*j+1] : px[2*j];
        tyc[j] = c ? py[2*j+1] : py[2*j];
        tzc[j] = c ? pz[2*j+1] : pz[2*j];
      }
      #pragma unroll
      for (int j = 0; j < 4; ++j) {
        bool c = tv[2*j+1] > tv[2*j];
        tv[j] = c ? tv[2*j+1] : tv[2*j]; tj[j] = c ? tj[2*j+1] : tj[2*j];
        txc[j] = c ? txc[2*j+1] : txc[2*j]; tyc[j] = c ? tyc[2*j+1] : tyc[2*j];
        tzc[j] = c ? tzc[2*j+1] : tzc[2*j];
      }
      #pragma unroll
      for (int j = 0; j < 2; ++j) {
        bool c = tv[2*j+1] > tv[2*j];
        tv[j] = c ? tv[2*j+1] : tv[2*j]; tj[j] = c ? tj[2*j+1] : tj[2*j];
        txc[j] = c ? txc[2*j+1] : txc[2*j]; tyc[j] = c ? tyc[2*j+1] : tyc[2*j];
        tzc[j] = c ? tzc[2*j+1] : tzc[2*j];
      }
      bool c = tv[1] > tv[0];
      bv = c ? tv[1] : tv[0];
      bi = t*16 + (c ? tj[1] : tj[0]);
      bx = c ? txc[1] : txc[0]; by = c ? tyc[1] : tyc[0]; bz = c ? tzc[1] : tzc[0];
    }
  }
  __syncthreads();
  // ---- coalesced output pass -----------------------------------------------
  for (int c = t; c < MPC; c += 256) {
    float4 q = cst[c];
    const int il = __float_as_int(q.w);
    const int cl = b*MPC + c;
    centers[cl] = make_float4(q.x, q.y, q.z, 0.0f);
    out[OFF_SUBPOS + cl*3 + 0] = q.x;
    out[OFF_SUBPOS + cl*3 + 1] = q.y;
    out[OFF_SUBPOS + cl*3 + 2] = q.z;
    out[OFF_SUBB + cl] = (float)b;
    out[OFF_IDCL + cl] = (float)(b*NPC + il);
  }
}

// ---------------- GEMM h = x@W + b, plus BN sum/sumsq accumulation ----------
__global__ __launch_bounds__(256) void gemm_kernel(const float* __restrict__ x,
                                                   const float* __restrict__ W,
                                                   const float* __restrict__ bias,
                                                   float* __restrict__ h,
                                                   float* __restrict__ stats)
{
  __shared__ float xT[64][68];     // [k][row], padded to kill bank conflicts
  __shared__ float Wl[64][128];
  __shared__ float bsum[128], bsq[128];
  const int t = threadIdx.x;
  const int blk = blockIdx.x;
  const int row0 = blk * 64;
  if (t < 128) { bsum[t] = 0.0f; bsq[t] = 0.0f; }
  #pragma unroll
  for (int i = 0; i < 16; ++i) {
    const int idx = t + i*256;
    xT[idx & 63][idx >> 6] = x[(size_t)row0*64 + idx];
  }
  #pragma unroll
  for (int i = 0; i < 32; ++i) {
    const int idx = t + i*256;
    ((float*)Wl)[idx] = W[idx];
  }
  __syncthreads();
  const int tx = t & 15, ty = t >> 4;   // 16x16 threads, 4 rows x 8 cols each
  float acc[4][8] = {};
  #pragma unroll 8
  for (int k = 0; k < 64; ++k) {
    const float4 a  = *(const float4*)&xT[k][ty*4];
    const float4 b0 = *(const float4*)&Wl[k][tx*8];
    const float4 b1 = *(const float4*)&Wl[k][tx*8+4];
    const float av[4] = {a.x, a.y, a.z, a.w};
    const float bw[8] = {b0.x,b0.y,b0.z,b0.w,b1.x,b1.y,b1.z,b1.w};
    #pragma unroll
    for (int i2 = 0; i2 < 4; ++i2)
      #pragma unroll
      for (int e = 0; e < 8; ++e)
        acc[i2][e] += av[i2] * bw[e];
  }
  const int c0 = tx*8;
  float bb[8];
  #pragma unroll
  for (int e = 0; e < 8; ++e) bb[e] = bias[c0+e];
  float s8[8] = {}, q8[8] = {};
  #pragma unroll
  for (int i2 = 0; i2 < 4; ++i2) {
    float vv[8];
    #pragma unroll
    for (int e = 0; e < 8; ++e) {
      float v = acc[i2][e] + bb[e];
      vv[e] = v; s8[e] += v; q8[e] += v*v;
    }
    const int r = row0 + ty*4 + i2;
    float4* dst = (float4*)&h[(size_t)r*128 + c0];
    dst[0] = make_float4(vv[0], vv[1], vv[2], vv[3]);
    dst[1] = make_float4(vv[4], vv[5], vv[6], vv[7]);
  }
  #pragma unroll
  for (int e = 0; e < 8; ++e) {
    atomicAdd(&bsum[c0+e], s8[e]);
    atomicAdd(&bsq[c0+e],  q8[e]);
  }
  __syncthreads();
  if (t < 128) {
    atomicAdd(&stats[t],      bsum[t]);
    atomicAdd(&stats[128+t],  bsq[t]);
  }
}

// ---------------- BN finalize: scale/shift per column -----------------------
__global__ __launch_bounds__(128) void bn_finalize(const float* __restrict__ stats,
                                                   const float* __restrict__ gamma,
                                                   const float* __restrict__ beta,
                                                   float* __restrict__ ss)
{
  const int t = threadIdx.x;
  const float inv = 1.0f / 65536.0f;
  const float mu  = stats[t] * inv;
  const float var = stats[128+t] * inv - mu*mu;
  const float sc  = gamma[t] * rsqrtf(var + 1e-5f);
  ss[t]      = sc;
  ss[128+t]  = beta[t] - mu*sc;
}

// ---------------- kNN: 8 threads per center, exact (d2, idx) top-16 ---------
__global__ __launch_bounds__(256) void knn_kernel(const float* __restrict__ pos,
                                                  const float4* __restrict__ centers,
                                                  int* __restrict__ nn)
{
  #pragma clang fp contract(off)
  __shared__ float4 lp[NPC];        // 64KB; reused as candidate scratch after scan
  const int blk = blockIdx.x;       // 512 blocks; 32 per cloud
  const int b   = blk >> 5;
  const int c0  = (blk & 31) * 32;  // first local center of this block
  const int t   = threadIdx.x;
  const int q   = t & 7;            // subset
  const int cc  = t >> 3;           // center within block, 0..31
  const float* pb = pos + (size_t)b * NPC * 3;
  for (int i = t; i < NPC; i += 256)
    lp[i] = make_float4(pb[3*i], pb[3*i+1], pb[3*i+2], 0.0f);
  __syncthreads();
  const int cg = b*MPC + c0 + cc;   // global cluster index
  const float4 C = centers[cg];
  float dsl[16]; int isl[16];
  #pragma unroll
  for (int k = 0; k < 16; ++k) { dsl[k] = INFINITY; isl[k] = 0x7fffffff; }
  float wv = INFINITY; int wi = 0x7fffffff; int wslot = 0;
  for (int jj = 0; jj < NPC/8; ++jj) {
    const int j = jj*8 + q;         // strictly increasing within thread
    const float4 p = lp[j];
    float dx = C.x - p.x, dy = C.y - p.y, dz = C.z - p.z;
    float d2 = (dx*dx + dy*dy) + dz*dz;   // no-FMA
    if (d2 < wv || (d2 == wv && j < wi)) {
      #pragma unroll
      for (int k = 0; k < 16; ++k) if (k == wslot) { dsl[k] = d2; isl[k] = j; }
      wv = dsl[0]; wi = isl[0]; wslot = 0;
      #pragma unroll
      for (int k = 1; k < 16; ++k)
        if (dsl[k] > wv || (dsl[k] == wv && isl[k] > wi)) { wv = dsl[k]; wi = isl[k]; wslot = k; }
    }
  }
  __syncthreads();                  // pos data no longer needed
  float* cd = (float*)lp;           // [32 centers][8 subsets][16]
  int*   ci = ((int*)lp) + 32*8*16;
  #pragma unroll
  for (int k = 0; k < 16; ++k) {
    cd[(cc*8 + q)*16 + k] = dsl[k];
    ci[(cc*8 + q)*16 + k] = isl[k];
  }
  __syncthreads();
  if (q == 0) {
    // merge 128 candidates lexicographically by (d2, idx) -> exact top-16 set
    float md[16]; int mi[16];
    #pragma unroll
    for (int k = 0; k < 16; ++k) { md[k] = INFINITY; mi[k] = 0x7fffffff; }
    float w2 = INFINITY; int w2i = 0x7fffffff; int w2s = 0;
    for (int e = 0; e < 128; ++e) {
      const float d  = cd[cc*128 + e];
      const int   id = ci[cc*128 + e];
      if (d < w2 || (d == w2 && id < w2i)) {
        #pragma unroll
        for (int k = 0; k < 16; ++k) if (k == w2s) { md[k] = d; mi[k] = id; }
        w2 = md[0]; w2i = mi[0]; w2s = 0;
        #pragma unroll
        for (int k = 1; k < 16; ++k)
          if (md[k] > w2 || (md[k] == w2 && mi[k] > w2i)) { w2 = md[k]; w2i = mi[k]; w2s = k; }
      }
    }
    #pragma unroll
    for (int k = 0; k < 16; ++k) nn[cg*16 + k] = b*NPC + mi[k];
  }
}

// ---------------- Pool: per-cluster max(relu(bn(h))) + mean(aux) ------------
__global__ __launch_bounds__(128) void pool_kernel(const float* __restrict__ h,
                                                   const float* __restrict__ aux,
                                                   const int* __restrict__ nn,
                                                   const float* __restrict__ ss,
                                                   float* __restrict__ out)
{
  __shared__ int ids[16];
  const int cl = blockIdx.x;
  const int t  = threadIdx.x;
  if (t < 16) ids[t] = nn[cl*16 + t];
  __syncthreads();
  const float sc = ss[t], sh = ss[128+t];
  float mv = 0.0f;                        // relu output >= 0, so 0 == -inf here
  #pragma unroll
  for (int k = 0; k < 16; ++k) {
    const float hv = h[(size_t)ids[k]*128 + t];
    mv = fmaxf(mv, fmaxf(sc*hv + sh, 0.0f));
  }
  out[OFF_XOUT + (size_t)cl*128 + t] = mv;
  if (t < 32) {
    float s = 0.0f;
    #pragma unroll
    for (int k = 0; k < 16; ++k) s += aux[(size_t)ids[k]*32 + t];
    out[OFF_AUX + (size_t)cl*32 + t] = s * (1.0f/16.0f);
  }
}

extern "C" void kernel_launch(void* const* d_in, const int* in_sizes, int n_in,
                              void* d_out, int out_size, void* d_ws, size_t ws_size,
                              hipStream_t stream)
{
  const float* x     = (const float*)d_in[0];
  const float* pos   = (const float*)d_in[1];
  // d_in[2] = batch (int32) — clouds are equal-size, derived analytically
  const float* aux   = (const float*)d_in[3];
  const float* W     = (const float*)d_in[4];
  const float* bias  = (const float*)d_in[5];
  const float* gamma = (const float*)d_in[6];
  const float* beta  = (const float*)d_in[7];
  float* out = (float*)d_out;
  char*  ws  = (char*)d_ws;
  if (ws_size < (size_t)WS_NEED) return;   // insufficient scratch: bail cleanly

  float*  h       = (float*)(ws + WS_H);
  float4* centers = (float4*)(ws + WS_CENTERS);
  int*    nn      = (int*)(ws + WS_NN);
  float*  stats   = (float*)(ws + WS_STATS);
  float*  ss      = (float*)(ws + WS_SS);

  hipMemsetAsync(stats, 0, 256*4, stream);  // BN accumulators: zero every call
  hipLaunchKernelGGL(fps_kernel,  dim3(NB),       dim3(256),  0, stream, pos, centers, out);
  hipLaunchKernelGGL(gemm_kernel, dim3(PTOT/64),  dim3(256),  0, stream, x, W, bias, h, stats);
  hipLaunchKernelGGL(bn_finalize, dim3(1),        dim3(128),  0, stream, stats, gamma, beta, ss);
  hipLaunchKernelGGL(knn_kernel,  dim3(512),      dim3(256),  0, stream, pos, centers, nn);
  hipLaunchKernelGGL(pool_kernel, dim3(NCLU),     dim3(128),  0, stream, h, aux, nn, ss, out);
}

// Round 4
// 1965.509 us; speedup vs baseline: 2.4379x; 2.4379x over previous
//
#include <hip/hip_runtime.h>
#include <hip/hip_bf16.h>
#include <math.h>

#define NB    16
#define NPC   4096        // points per cloud
#define MPC   1024        // clusters per cloud
#define PTOT  65536
#define NCLU  16384
#define KNN_  16
#define CIN   64
#define COUT_ 128
#define CAUX_ 32

// out offsets (float elements), outputs concatenated in reference return order
#define OFF_XOUT   0
#define OFF_SUBPOS (NCLU*COUT_)               // 2097152
#define OFF_SUBB   (OFF_SUBPOS + NCLU*3)      // 2146304
#define OFF_AUX    (OFF_SUBB + NCLU)          // 2162688
#define OFF_IDCL   (OFF_AUX + NCLU*CAUX_)     // 2686976

// ws offsets (bytes)
#define WS_H        0
#define WS_CENTERS  (PTOT*COUT_*4)            // 33554432  (h: P x 128 f32)
#define WS_NN       (WS_CENTERS + NCLU*16)    // centers: float4 per cluster
#define WS_STATS    (WS_NN + NCLU*KNN_*4)     // nn ids
#define WS_SS       (WS_STATS + 256*4)        // sum[128], sumsq[128]
#define WS_NEED     (WS_SS + 256*4)           // scale[128], shift[128]

// ---- shared-memory overlay for the fused fps/gemm kernel -------------------
// fps view:
#define SM_LX    0                      // 4096 f  (16384 B)
#define SM_LY    16384
#define SM_LZ    32768
#define SM_CAND  49152                  // 256 u64 (2048 B)
#define SM_WIN   51200                  // 16 u64  (128 B)
#define SM_CST   51328                  // 1024 float4 (16384 B) -> 67712
// gemm view:
#define SM_XT    0                      // float[64][68] = 17408 B
#define SM_WL    17408                  // float[64][128] = 32768 B -> 50176
#define SM_BS    50176                  // float[128]
#define SM_BQ    50688                  // float[128] -> 51200
#define SM_SIZE  67712

typedef unsigned long long ull;

__device__ __forceinline__ ull packkey(float d, int jg) {
  // d >= 0 so raw float bits sort monotonically; larger (4095-jg) == smaller jg.
  return ((ull)__float_as_uint(d) << 32) | (unsigned)(4095 - jg);
}
__device__ __forceinline__ ull umax(ull a, ull b) { return a > b ? a : b; }

// tree-reduce 16 u64 keys starting at p (LDS), via 8 pipelined b128 reads
__device__ __forceinline__ ull tree16(const ull* p) {
  const ulonglong2* q = (const ulonglong2*)p;
  ulonglong2 q0 = q[0], q1 = q[1], q2 = q[2], q3 = q[3];
  ulonglong2 q4 = q[4], q5 = q[5], q6 = q[6], q7 = q[7];
  ull a = umax(umax(umax(q0.x, q0.y), umax(q1.x, q1.y)),
               umax(umax(q2.x, q2.y), umax(q3.x, q3.y)));
  ull b = umax(umax(umax(q4.x, q4.y), umax(q5.x, q5.y)),
               umax(umax(q6.x, q6.y), umax(q7.x, q7.y)));
  return umax(a, b);
}

// ---------------- FPS block: two-stage LDS tournament, no cross-lane ops ----
__device__ void fps_block(char* smem, const float* __restrict__ pos,
                          float4* __restrict__ centers, float* __restrict__ out)
{
  #pragma clang fp contract(off)
  float* lx = (float*)(smem + SM_LX);
  float* ly = (float*)(smem + SM_LY);
  float* lz = (float*)(smem + SM_LZ);
  ull*   cand = (ull*)(smem + SM_CAND);
  ull*   win  = (ull*)(smem + SM_WIN);
  float4* cst = (float4*)(smem + SM_CST);
  const int b = blockIdx.x;
  const int t = threadIdx.x;
  const float* pb = pos + (size_t)b * NPC * 3;

  // Each thread owns 16 consecutive points (in-cloud idx t*16 .. t*16+15).
  float px[16], py[16], pz[16], mind[16];
  {
    const float4* src = (const float4*)(pb + t * 48);
    float4 v[12];
    #pragma unroll
    for (int i = 0; i < 12; ++i) v[i] = src[i];
    const float* f = (const float*)v;
    #pragma unroll
    for (int j = 0; j < 16; ++j) {
      px[j] = f[3*j]; py[j] = f[3*j+1]; pz[j] = f[3*j+2];
      lx[t*16+j] = px[j]; ly[t*16+j] = py[j]; lz[t*16+j] = pz[j];
    }
  }
  __syncthreads();
  const float x0 = lx[0], y0 = ly[0], z0 = lz[0];
  if (t == 0) cst[0] = make_float4(x0, y0, z0, __int_as_float(0));

  // initial distances to point 0 + per-thread best key
  ull bk;
  {
    ull k8[8];
    #pragma unroll
    for (int jp = 0; jp < 8; ++jp) {
      const int j0 = 2*jp, j1 = 2*jp + 1;
      float dx0 = px[j0]-x0, dy0 = py[j0]-y0, dz0 = pz[j0]-z0;
      float dx1 = px[j1]-x0, dy1 = py[j1]-y0, dz1 = pz[j1]-z0;
      float d0 = (dx0*dx0 + dy0*dy0) + dz0*dz0;   // no-FMA: matches numpy
      float d1 = (dx1*dx1 + dy1*dy1) + dz1*dz1;
      mind[j0] = d0; mind[j1] = d1;
      k8[jp] = umax(packkey(d0, t*16+j0), packkey(d1, t*16+j1));
    }
    ull k40 = umax(k8[0], k8[1]), k41 = umax(k8[2], k8[3]);
    ull k42 = umax(k8[4], k8[5]), k43 = umax(k8[6], k8[7]);
    bk = umax(umax(k40, k41), umax(k42, k43));
  }

  for (int s = 1; s < MPC; ++s) {
    cand[t] = bk;
    __syncthreads();
    // stage B: 16 threads per slice reduce it redundantly -> identical value
    const int slice = t & 15;
    win[slice] = tree16(cand + slice*16);        // benign same-value race
    __syncthreads();
    // stage C: every thread reduces the 16 slice winners
    const ull wk = tree16(win);
    const int sel = 4095 - (int)(unsigned)(wk & 0xFFFFFFFFull);
    const float sx = lx[sel], sy = ly[sel], sz = lz[sel];  // broadcast reads
    if (t == 0) cst[s] = make_float4(sx, sy, sz, __int_as_float(sel));
    // distance update + fresh per-thread best
    ull k8[8];
    #pragma unroll
    for (int jp = 0; jp < 8; ++jp) {
      const int j0 = 2*jp, j1 = 2*jp + 1;
      float dx0 = px[j0]-sx, dy0 = py[j0]-sy, dz0 = pz[j0]-sz;
      float dx1 = px[j1]-sx, dy1 = py[j1]-sy, dz1 = pz[j1]-sz;
      float d0 = (dx0*dx0 + dy0*dy0) + dz0*dz0;
      float d1 = (dx1*dx1 + dy1*dy1) + dz1*dz1;
      float m0 = fminf(mind[j0], d0), m1 = fminf(mind[j1], d1);
      mind[j0] = m0; mind[j1] = m1;
      k8[jp] = umax(packkey(m0, t*16+j0), packkey(m1, t*16+j1));
    }
    ull k40 = umax(k8[0], k8[1]), k41 = umax(k8[2], k8[3]);
    ull k42 = umax(k8[4], k8[5]), k43 = umax(k8[6], k8[7]);
    bk = umax(umax(k40, k41), umax(k42, k43));
  }
  __syncthreads();
  // coalesced output pass
  for (int c = t; c < MPC; c += 256) {
    float4 q = cst[c];
    const int il = __float_as_int(q.w);
    const int cl = b*MPC + c;
    centers[cl] = make_float4(q.x, q.y, q.z, 0.0f);
    out[OFF_SUBPOS + cl*3 + 0] = q.x;
    out[OFF_SUBPOS + cl*3 + 1] = q.y;
    out[OFF_SUBPOS + cl*3 + 2] = q.z;
    out[OFF_SUBB + cl] = (float)b;
    out[OFF_IDCL + cl] = (float)(b*NPC + il);
  }
}

// ---------------- GEMM block: h = x@W + b, plus BN sum/sumsq ----------------
__device__ void gemm_block(char* smem, const float* __restrict__ x,
                           const float* __restrict__ W, const float* __restrict__ bias,
                           float* __restrict__ h, float* __restrict__ stats, int blk)
{
  float (*xT)[68]  = (float(*)[68])(smem + SM_XT);   // [k][row], padded
  float (*Wl)[128] = (float(*)[128])(smem + SM_WL);
  float* bsum = (float*)(smem + SM_BS);
  float* bsq  = (float*)(smem + SM_BQ);
  const int t = threadIdx.x;
  const int row0 = blk * 64;
  if (t < 128) { bsum[t] = 0.0f; bsq[t] = 0.0f; }
  #pragma unroll
  for (int i = 0; i < 16; ++i) {
    const int idx = t + i*256;
    xT[idx & 63][idx >> 6] = x[(size_t)row0*64 + idx];
  }
  #pragma unroll
  for (int i = 0; i < 32; ++i) {
    const int idx = t + i*256;
    ((float*)Wl)[idx] = W[idx];
  }
  __syncthreads();
  const int tx = t & 15, ty = t >> 4;   // 16x16 threads, 4 rows x 8 cols each
  float acc[4][8] = {};
  #pragma unroll 8
  for (int k = 0; k < 64; ++k) {
    const float4 a  = *(const float4*)&xT[k][ty*4];
    const float4 b0 = *(const float4*)&Wl[k][tx*8];
    const float4 b1 = *(const float4*)&Wl[k][tx*8+4];
    const float av[4] = {a.x, a.y, a.z, a.w};
    const float bw[8] = {b0.x,b0.y,b0.z,b0.w,b1.x,b1.y,b1.z,b1.w};
    #pragma unroll
    for (int i2 = 0; i2 < 4; ++i2)
      #pragma unroll
      for (int e = 0; e < 8; ++e)
        acc[i2][e] += av[i2] * bw[e];
  }
  const int c0 = tx*8;
  float bb[8];
  #pragma unroll
  for (int e = 0; e < 8; ++e) bb[e] = bias[c0+e];
  float s8[8] = {}, q8[8] = {};
  #pragma unroll
  for (int i2 = 0; i2 < 4; ++i2) {
    float vv[8];
    #pragma unroll
    for (int e = 0; e < 8; ++e) {
      float v = acc[i2][e] + bb[e];
      vv[e] = v; s8[e] += v; q8[e] += v*v;
    }
    const int r = row0 + ty*4 + i2;
    float4* dst = (float4*)&h[(size_t)r*128 + c0];
    dst[0] = make_float4(vv[0], vv[1], vv[2], vv[3]);
    dst[1] = make_float4(vv[4], vv[5], vv[6], vv[7]);
  }
  #pragma unroll
  for (int e = 0; e < 8; ++e) {
    atomicAdd(&bsum[c0+e], s8[e]);
    atomicAdd(&bsq[c0+e],  q8[e]);
  }
  __syncthreads();
  if (t < 128) {
    atomicAdd(&stats[t],      bsum[t]);
    atomicAdd(&stats[128+t],  bsq[t]);
  }
}

// ---------------- fused launcher kernel -------------------------------------
__global__ __launch_bounds__(256) void fused_fps_gemm(const float* __restrict__ pos,
                                                      float4* __restrict__ centers,
                                                      float* __restrict__ out,
                                                      const float* __restrict__ x,
                                                      const float* __restrict__ W,
                                                      const float* __restrict__ bias,
                                                      float* __restrict__ h,
                                                      float* __restrict__ stats)
{
  __shared__ __align__(16) char smem[SM_SIZE];
  if (blockIdx.x < NB) fps_block(smem, pos, centers, out);
  else                 gemm_block(smem, x, W, bias, h, stats, blockIdx.x - NB);
}

// ---------------- BN finalize: scale/shift per column -----------------------
__global__ __launch_bounds__(128) void bn_finalize(const float* __restrict__ stats,
                                                   const float* __restrict__ gamma,
                                                   const float* __restrict__ beta,
                                                   float* __restrict__ ss)
{
  const int t = threadIdx.x;
  const float inv = 1.0f / 65536.0f;
  const float mu  = stats[t] * inv;
  const float var = stats[128+t] * inv - mu*mu;
  const float sc  = gamma[t] * rsqrtf(var + 1e-5f);
  ss[t]      = sc;
  ss[128+t]  = beta[t] - mu*sc;
}

// ---------------- kNN: 8 threads per center, exact (d2, idx) top-16 ---------
__global__ __launch_bounds__(256) void knn_kernel(const float* __restrict__ pos,
                                                  const float4* __restrict__ centers,
                                                  int* __restrict__ nn)
{
  #pragma clang fp contract(off)
  __shared__ float4 lp[NPC];        // 64KB; reused as candidate scratch after scan
  const int blk = blockIdx.x;       // 512 blocks; 32 per cloud
  const int b   = blk >> 5;
  const int c0  = (blk & 31) * 32;  // first local center of this block
  const int t   = threadIdx.x;
  const int q   = t & 7;            // subset
  const int cc  = t >> 3;           // center within block, 0..31
  const float* pb = pos + (size_t)b * NPC * 3;
  for (int i = t; i < NPC; i += 256)
    lp[i] = make_float4(pb[3*i], pb[3*i+1], pb[3*i+2], 0.0f);
  __syncthreads();
  const int cg = b*MPC + c0 + cc;   // global cluster index
  const float4 C = centers[cg];
  float dsl[16]; int isl[16];
  #pragma unroll
  for (int k = 0; k < 16; ++k) { dsl[k] = INFINITY; isl[k] = 0x7fffffff; }
  float wv = INFINITY; int wi = 0x7fffffff; int wslot = 0;
  for (int jj = 0; jj < NPC/8; ++jj) {
    const int j = jj*8 + q;         // strictly increasing within thread
    const float4 p = lp[j];
    float dx = C.x - p.x, dy = C.y - p.y, dz = C.z - p.z;
    float d2 = (dx*dx + dy*dy) + dz*dz;   // no-FMA
    if (d2 < wv || (d2 == wv && j < wi)) {
      #pragma unroll
      for (int k = 0; k < 16; ++k) if (k == wslot) { dsl[k] = d2; isl[k] = j; }
      wv = dsl[0]; wi = isl[0]; wslot = 0;
      #pragma unroll
      for (int k = 1; k < 16; ++k)
        if (dsl[k] > wv || (dsl[k] == wv && isl[k] > wi)) { wv = dsl[k]; wi = isl[k]; wslot = k; }
    }
  }
  __syncthreads();                  // pos data no longer needed
  float* cd = (float*)lp;           // [32 centers][8 subsets][16]
  int*   ci = ((int*)lp) + 32*8*16;
  #pragma unroll
  for (int k = 0; k < 16; ++k) {
    cd[(cc*8 + q)*16 + k] = dsl[k];
    ci[(cc*8 + q)*16 + k] = isl[k];
  }
  __syncthreads();
  if (q == 0) {
    // merge 128 candidates lexicographically by (d2, idx) -> exact top-16 set
    float md[16]; int mi[16];
    #pragma unroll
    for (int k = 0; k < 16; ++k) { md[k] = INFINITY; mi[k] = 0x7fffffff; }
    float w2 = INFINITY; int w2i = 0x7fffffff; int w2s = 0;
    for (int e = 0; e < 128; ++e) {
      const float d  = cd[cc*128 + e];
      const int   id = ci[cc*128 + e];
      if (d < w2 || (d == w2 && id < w2i)) {
        #pragma unroll
        for (int k = 0; k < 16; ++k) if (k == w2s) { md[k] = d; mi[k] = id; }
        w2 = md[0]; w2i = mi[0]; w2s = 0;
        #pragma unroll
        for (int k = 1; k < 16; ++k)
          if (md[k] > w2 || (md[k] == w2 && mi[k] > w2i)) { w2 = md[k]; w2i = mi[k]; w2s = k; }
      }
    }
    #pragma unroll
    for (int k = 0; k < 16; ++k) nn[cg*16 + k] = b*NPC + mi[k];
  }
}

// ---------------- Pool: per-cluster max(relu(bn(h))) + mean(aux) ------------
__global__ __launch_bounds__(128) void pool_kernel(const float* __restrict__ h,
                                                   const float* __restrict__ aux,
                                                   const int* __restrict__ nn,
                                                   const float* __restrict__ ss,
                                                   float* __restrict__ out)
{
  __shared__ int ids[16];
  const int cl = blockIdx.x;
  const int t  = threadIdx.x;
  if (t < 16) ids[t] = nn[cl*16 + t];
  __syncthreads();
  const float sc = ss[t], sh = ss[128+t];
  float mv = 0.0f;                        // relu output >= 0, so 0 == -inf here
  #pragma unroll
  for (int k = 0; k < 16; ++k) {
    const float hv = h[(size_t)ids[k]*128 + t];
    mv = fmaxf(mv, fmaxf(sc*hv + sh, 0.0f));
  }
  out[OFF_XOUT + (size_t)cl*128 + t] = mv;
  if (t < 32) {
    float s = 0.0f;
    #pragma unroll
    for (int k = 0; k < 16; ++k) s += aux[(size_t)ids[k]*32 + t];
    out[OFF_AUX + (size_t)cl*32 + t] = s * (1.0f/16.0f);
  }
}

extern "C" void kernel_launch(void* const* d_in, const int* in_sizes, int n_in,
                              void* d_out, int out_size, void* d_ws, size_t ws_size,
                              hipStream_t stream)
{
  const float* x     = (const float*)d_in[0];
  const float* pos   = (const float*)d_in[1];
  // d_in[2] = batch (int32) — clouds are equal-size, derived analytically
  const float* aux   = (const float*)d_in[3];
  const float* W     = (const float*)d_in[4];
  const float* bias  = (const float*)d_in[5];
  const float* gamma = (const float*)d_in[6];
  const float* beta  = (const float*)d_in[7];
  float* out = (float*)d_out;
  char*  ws  = (char*)d_ws;
  if (ws_size < (size_t)WS_NEED) return;   // insufficient scratch: bail cleanly

  float*  h       = (float*)(ws + WS_H);
  float4* centers = (float4*)(ws + WS_CENTERS);
  int*    nn      = (int*)(ws + WS_NN);
  float*  stats   = (float*)(ws + WS_STATS);
  float*  ss      = (float*)(ws + WS_SS);

  hipMemsetAsync(stats, 0, 256*4, stream);  // BN accumulators: zero every call
  hipLaunchKernelGGL(fused_fps_gemm, dim3(NB + PTOT/64), dim3(256), 0, stream,
                     pos, centers, out, x, W, bias, h, stats);
  hipLaunchKernelGGL(bn_finalize, dim3(1),    dim3(128), 0, stream, stats, gamma, beta, ss);
  hipLaunchKernelGGL(knn_kernel,  dim3(512),  dim3(256), 0, stream, pos, centers, nn);
  hipLaunchKernelGGL(pool_kernel, dim3(NCLU), dim3(128), 0, stream, h, aux, nn, ss, out);
}

// Round 5
// 1671.168 us; speedup vs baseline: 2.8673x; 1.1761x over previous
//
#include <hip/hip_runtime.h>
#include <hip/hip_bf16.h>
#include <math.h>

#define NB    16
#define NPC   4096        // points per cloud
#define MPC   1024        // clusters per cloud
#define PTOT  65536
#define NCLU  16384
#define KNN_  16
#define CIN   64
#define COUT_ 128
#define CAUX_ 32

// out offsets (float elements), outputs concatenated in reference return order
#define OFF_XOUT   0
#define OFF_SUBPOS (NCLU*COUT_)               // 2097152
#define OFF_SUBB   (OFF_SUBPOS + NCLU*3)      // 2146304
#define OFF_AUX    (OFF_SUBB + NCLU)          // 2162688
#define OFF_IDCL   (OFF_AUX + NCLU*CAUX_)     // 2686976

// ws offsets (bytes)
#define WS_H        0
#define WS_CENTERS  (PTOT*COUT_*4)            // 33554432  (h: P x 128 f32)
#define WS_NN       (WS_CENTERS + NCLU*16)    // centers: float4 per cluster
#define WS_STATS    (WS_NN + NCLU*KNN_*4)     // nn ids
#define WS_SS       (WS_STATS + 256*4)        // sum[128], sumsq[128]
#define WS_NEED     (WS_SS + 256*4)           // scale[128], shift[128]

// ---- shared-memory overlay for the fused fps/gemm kernel -------------------
// fps view (CAND padded to stride 18 u64 = 144B: stage-B reads 2-way, not 16-way)
#define CAND_STRIDE 18
#define SM_LX    0                      // 4096 f  (16384 B)
#define SM_LY    16384
#define SM_LZ    32768
#define SM_CAND  49152                  // 16 slices * 18 u64 = 2304 B
#define SM_WIN   51456                  // 16 u64  (128 B)
#define SM_CST   51584                  // 1024 float4 (16384 B) -> 67968
// gemm view:
#define SM_XT    0                      // float[64][68] = 17408 B
#define SM_WL    17408                  // float[64][128] = 32768 B -> 50176
#define SM_BS    50176                  // float[128]
#define SM_BQ    50688                  // float[128] -> 51200
#define SM_SIZE  67968

typedef unsigned long long ull;

__device__ __forceinline__ ull packkey(float d, int jg) {
  // d >= 0 so raw float bits sort monotonically; larger (4095-jg) == smaller jg.
  return ((ull)__float_as_uint(d) << 32) | (unsigned)(4095 - jg);
}
__device__ __forceinline__ ull umax(ull a, ull b) { return a > b ? a : b; }

// tree-reduce 16 u64 keys starting at p (LDS), via 8 pipelined b128 reads
__device__ __forceinline__ ull tree16(const ull* p) {
  const ulonglong2* q = (const ulonglong2*)p;
  ulonglong2 q0 = q[0], q1 = q[1], q2 = q[2], q3 = q[3];
  ulonglong2 q4 = q[4], q5 = q[5], q6 = q[6], q7 = q[7];
  ull a = umax(umax(umax(q0.x, q0.y), umax(q1.x, q1.y)),
               umax(umax(q2.x, q2.y), umax(q3.x, q3.y)));
  ull b = umax(umax(umax(q4.x, q4.y), umax(q5.x, q5.y)),
               umax(umax(q6.x, q6.y), umax(q7.x, q7.y)));
  return umax(a, b);
}

// ---------------- FPS block: two-stage LDS tournament, no cross-lane ops ----
__device__ void fps_block(char* smem, const float* __restrict__ pos,
                          float4* __restrict__ centers, float* __restrict__ out)
{
  #pragma clang fp contract(off)
  float* lx = (float*)(smem + SM_LX);
  float* ly = (float*)(smem + SM_LY);
  float* lz = (float*)(smem + SM_LZ);
  ull*   cand = (ull*)(smem + SM_CAND);
  ull*   win  = (ull*)(smem + SM_WIN);
  float4* cst = (float4*)(smem + SM_CST);
  const int b = blockIdx.x;
  const int t = threadIdx.x;
  const float* pb = pos + (size_t)b * NPC * 3;
  const int myslot = (t >> 4) * CAND_STRIDE + (t & 15);  // slice (t>>4), elem (t&15)

  // Each thread owns 16 consecutive points (in-cloud idx t*16 .. t*16+15).
  float px[16], py[16], pz[16], mind[16];
  {
    const float4* src = (const float4*)(pb + t * 48);
    float4 v[12];
    #pragma unroll
    for (int i = 0; i < 12; ++i) v[i] = src[i];
    const float* f = (const float*)v;
    #pragma unroll
    for (int j = 0; j < 16; ++j) {
      px[j] = f[3*j]; py[j] = f[3*j+1]; pz[j] = f[3*j+2];
      lx[t*16+j] = px[j]; ly[t*16+j] = py[j]; lz[t*16+j] = pz[j];
    }
  }
  __syncthreads();
  const float x0 = lx[0], y0 = ly[0], z0 = lz[0];
  if (t == 0) cst[0] = make_float4(x0, y0, z0, __int_as_float(0));

  // initial distances to point 0 + per-thread best key
  ull bk;
  {
    ull k8[8];
    #pragma unroll
    for (int jp = 0; jp < 8; ++jp) {
      const int j0 = 2*jp, j1 = 2*jp + 1;
      float dx0 = px[j0]-x0, dy0 = py[j0]-y0, dz0 = pz[j0]-z0;
      float dx1 = px[j1]-x0, dy1 = py[j1]-y0, dz1 = pz[j1]-z0;
      float d0 = (dx0*dx0 + dy0*dy0) + dz0*dz0;   // no-FMA: matches numpy
      float d1 = (dx1*dx1 + dy1*dy1) + dz1*dz1;
      mind[j0] = d0; mind[j1] = d1;
      k8[jp] = umax(packkey(d0, t*16+j0), packkey(d1, t*16+j1));
    }
    ull k40 = umax(k8[0], k8[1]), k41 = umax(k8[2], k8[3]);
    ull k42 = umax(k8[4], k8[5]), k43 = umax(k8[6], k8[7]);
    bk = umax(umax(k40, k41), umax(k42, k43));
  }

  for (int s = 1; s < MPC; ++s) {
    cand[myslot] = bk;
    __syncthreads();
    // stage B: 16 threads per slice reduce it redundantly -> identical value
    const int slice = t & 15;
    win[slice] = tree16(cand + slice*CAND_STRIDE);   // benign same-value race
    __syncthreads();
    // stage C: every thread reduces the 16 slice winners (broadcast reads)
    const ull wk = tree16(win);
    const int sel = 4095 - (int)(unsigned)(wk & 0xFFFFFFFFull);
    const float sx = lx[sel], sy = ly[sel], sz = lz[sel];  // broadcast reads
    if (t == 0) cst[s] = make_float4(sx, sy, sz, __int_as_float(sel));
    // distance update + fresh per-thread best
    ull k8[8];
    #pragma unroll
    for (int jp = 0; jp < 8; ++jp) {
      const int j0 = 2*jp, j1 = 2*jp + 1;
      float dx0 = px[j0]-sx, dy0 = py[j0]-sy, dz0 = pz[j0]-sz;
      float dx1 = px[j1]-sx, dy1 = py[j1]-sy, dz1 = pz[j1]-sz;
      float d0 = (dx0*dx0 + dy0*dy0) + dz0*dz0;
      float d1 = (dx1*dx1 + dy1*dy1) + dz1*dz1;
      float m0 = fminf(mind[j0], d0), m1 = fminf(mind[j1], d1);
      mind[j0] = m0; mind[j1] = m1;
      k8[jp] = umax(packkey(m0, t*16+j0), packkey(m1, t*16+j1));
    }
    ull k40 = umax(k8[0], k8[1]), k41 = umax(k8[2], k8[3]);
    ull k42 = umax(k8[4], k8[5]), k43 = umax(k8[6], k8[7]);
    bk = umax(umax(k40, k41), umax(k42, k43));
  }
  __syncthreads();
  // coalesced output pass
  for (int c = t; c < MPC; c += 256) {
    float4 q = cst[c];
    const int il = __float_as_int(q.w);
    const int cl = b*MPC + c;
    centers[cl] = make_float4(q.x, q.y, q.z, 0.0f);
    out[OFF_SUBPOS + cl*3 + 0] = q.x;
    out[OFF_SUBPOS + cl*3 + 1] = q.y;
    out[OFF_SUBPOS + cl*3 + 2] = q.z;
    out[OFF_SUBB + cl] = (float)b;
    out[OFF_IDCL + cl] = (float)(b*NPC + il);
  }
}

// ---------------- GEMM block: h = x@W + b, plus BN sum/sumsq ----------------
__device__ void gemm_block(char* smem, const float* __restrict__ x,
                           const float* __restrict__ W, const float* __restrict__ bias,
                           float* __restrict__ h, float* __restrict__ stats, int blk)
{
  float (*xT)[68]  = (float(*)[68])(smem + SM_XT);   // [k][row], padded
  float (*Wl)[128] = (float(*)[128])(smem + SM_WL);
  float* bsum = (float*)(smem + SM_BS);
  float* bsq  = (float*)(smem + SM_BQ);
  const int t = threadIdx.x;
  const int row0 = blk * 64;
  if (t < 128) { bsum[t] = 0.0f; bsq[t] = 0.0f; }
  #pragma unroll
  for (int i = 0; i < 16; ++i) {
    const int idx = t + i*256;
    xT[idx & 63][idx >> 6] = x[(size_t)row0*64 + idx];
  }
  #pragma unroll
  for (int i = 0; i < 32; ++i) {
    const int idx = t + i*256;
    ((float*)Wl)[idx] = W[idx];
  }
  __syncthreads();
  const int tx = t & 15, ty = t >> 4;   // 16x16 threads, 4 rows x 8 cols each
  float acc[4][8] = {};
  #pragma unroll 8
  for (int k = 0; k < 64; ++k) {
    const float4 a  = *(const float4*)&xT[k][ty*4];
    const float4 b0 = *(const float4*)&Wl[k][tx*8];
    const float4 b1 = *(const float4*)&Wl[k][tx*8+4];
    const float av[4] = {a.x, a.y, a.z, a.w};
    const float bw[8] = {b0.x,b0.y,b0.z,b0.w,b1.x,b1.y,b1.z,b1.w};
    #pragma unroll
    for (int i2 = 0; i2 < 4; ++i2)
      #pragma unroll
      for (int e = 0; e < 8; ++e)
        acc[i2][e] += av[i2] * bw[e];
  }
  const int c0 = tx*8;
  float bb[8];
  #pragma unroll
  for (int e = 0; e < 8; ++e) bb[e] = bias[c0+e];
  float s8[8] = {}, q8[8] = {};
  #pragma unroll
  for (int i2 = 0; i2 < 4; ++i2) {
    float vv[8];
    #pragma unroll
    for (int e = 0; e < 8; ++e) {
      float v = acc[i2][e] + bb[e];
      vv[e] = v; s8[e] += v; q8[e] += v*v;
    }
    const int r = row0 + ty*4 + i2;
    float4* dst = (float4*)&h[(size_t)r*128 + c0];
    dst[0] = make_float4(vv[0], vv[1], vv[2], vv[3]);
    dst[1] = make_float4(vv[4], vv[5], vv[6], vv[7]);
  }
  #pragma unroll
  for (int e = 0; e < 8; ++e) {
    atomicAdd(&bsum[c0+e], s8[e]);
    atomicAdd(&bsq[c0+e],  q8[e]);
  }
  __syncthreads();
  if (t < 128) {
    atomicAdd(&stats[t],      bsum[t]);
    atomicAdd(&stats[128+t],  bsq[t]);
  }
}

// ---------------- fused launcher kernel -------------------------------------
__global__ __launch_bounds__(256) void fused_fps_gemm(const float* __restrict__ pos,
                                                      float4* __restrict__ centers,
                                                      float* __restrict__ out,
                                                      const float* __restrict__ x,
                                                      const float* __restrict__ W,
                                                      const float* __restrict__ bias,
                                                      float* __restrict__ h,
                                                      float* __restrict__ stats)
{
  __shared__ __align__(16) char smem[SM_SIZE];
  if (blockIdx.x < NB) fps_block(smem, pos, centers, out);
  else                 gemm_block(smem, x, W, bias, h, stats, blockIdx.x - NB);
}

// ---------------- BN finalize: scale/shift per column -----------------------
__global__ __launch_bounds__(128) void bn_finalize(const float* __restrict__ stats,
                                                   const float* __restrict__ gamma,
                                                   const float* __restrict__ beta,
                                                   float* __restrict__ ss)
{
  const int t = threadIdx.x;
  const float inv = 1.0f / 65536.0f;
  const float mu  = stats[t] * inv;
  const float var = stats[128+t] * inv - mu*mu;
  const float sc  = gamma[t] * rsqrtf(var + 1e-5f);
  ss[t]      = sc;
  ss[128+t]  = beta[t] - mu*sc;
}

// ---------------- kNN: 8 threads per center, exact (d2, idx) top-16 ---------
__global__ __launch_bounds__(256) void knn_kernel(const float* __restrict__ pos,
                                                  const float4* __restrict__ centers,
                                                  int* __restrict__ nn)
{
  #pragma clang fp contract(off)
  __shared__ float4 lp[NPC];        // 64KB; reused as candidate scratch after scan
  const int blk = blockIdx.x;       // 512 blocks; 32 per cloud
  const int b   = blk >> 5;
  const int c0  = (blk & 31) * 32;  // first local center of this block
  const int t   = threadIdx.x;
  const int q   = t & 7;            // subset
  const int cc  = t >> 3;           // center within block, 0..31
  const float* pb = pos + (size_t)b * NPC * 3;
  for (int i = t; i < NPC; i += 256)
    lp[i] = make_float4(pb[3*i], pb[3*i+1], pb[3*i+2], 0.0f);
  __syncthreads();
  const int cg = b*MPC + c0 + cc;   // global cluster index
  const float4 C = centers[cg];
  float dsl[16]; int isl[16];
  #pragma unroll
  for (int k = 0; k < 16; ++k) { dsl[k] = INFINITY; isl[k] = 0x7fffffff; }
  float wv = INFINITY; int wi = 0x7fffffff; int wslot = 0;
  for (int jj = 0; jj < NPC/8; ++jj) {
    const int j = jj*8 + q;         // strictly increasing within thread
    const float4 p = lp[j];
    float dx = C.x - p.x, dy = C.y - p.y, dz = C.z - p.z;
    float d2 = (dx*dx + dy*dy) + dz*dz;   // no-FMA
    if (d2 < wv || (d2 == wv && j < wi)) {
      #pragma unroll
      for (int k = 0; k < 16; ++k) if (k == wslot) { dsl[k] = d2; isl[k] = j; }
      wv = dsl[0]; wi = isl[0]; wslot = 0;
      #pragma unroll
      for (int k = 1; k < 16; ++k)
        if (dsl[k] > wv || (dsl[k] == wv && isl[k] > wi)) { wv = dsl[k]; wi = isl[k]; wslot = k; }
    }
  }
  __syncthreads();                  // pos data no longer needed
  float* cd = (float*)lp;           // [32 centers][8 subsets][16]
  int*   ci = ((int*)lp) + 32*8*16;
  #pragma unroll
  for (int k = 0; k < 16; ++k) {
    cd[(cc*8 + q)*16 + k] = dsl[k];
    ci[(cc*8 + q)*16 + k] = isl[k];
  }
  __syncthreads();
  if (q == 0) {
    // merge 128 candidates lexicographically by (d2, idx) -> exact top-16 set
    float md[16]; int mi[16];
    #pragma unroll
    for (int k = 0; k < 16; ++k) { md[k] = INFINITY; mi[k] = 0x7fffffff; }
    float w2 = INFINITY; int w2i = 0x7fffffff; int w2s = 0;
    for (int e = 0; e < 128; ++e) {
      const float d  = cd[cc*128 + e];
      const int   id = ci[cc*128 + e];
      if (d < w2 || (d == w2 && id < w2i)) {
        #pragma unroll
        for (int k = 0; k < 16; ++k) if (k == w2s) { md[k] = d; mi[k] = id; }
        w2 = md[0]; w2i = mi[0]; w2s = 0;
        #pragma unroll
        for (int k = 1; k < 16; ++k)
          if (md[k] > w2 || (md[k] == w2 && mi[k] > w2i)) { w2 = md[k]; w2i = mi[k]; w2s = k; }
      }
    }
    #pragma unroll
    for (int k = 0; k < 16; ++k) nn[cg*16 + k] = b*NPC + mi[k];
  }
}

// ---------------- Pool: 2 clusters/block: max(relu(bn(h))) + mean(aux) ------
__global__ __launch_bounds__(256) void pool_kernel(const float* __restrict__ h,
                                                   const float* __restrict__ aux,
                                                   const int* __restrict__ nn,
                                                   const float* __restrict__ ss,
                                                   float* __restrict__ out)
{
  __shared__ int ids[2][16];
  const int t  = threadIdx.x;
  const int c  = t >> 7;                  // 0..1: cluster within block
  const int t2 = t & 127;                 // column
  const int cl = blockIdx.x * 2 + c;
  if (t2 < 16) ids[c][t2] = nn[cl*16 + t2];
  __syncthreads();
  const float sc = ss[t2], sh = ss[128+t2];
  float mv = 0.0f;                        // relu output >= 0, so 0 == -inf here
  #pragma unroll
  for (int k = 0; k < 16; ++k) {
    const float hv = h[(size_t)ids[c][k]*128 + t2];
    mv = fmaxf(mv, fmaxf(sc*hv + sh, 0.0f));
  }
  out[OFF_XOUT + (size_t)cl*128 + t2] = mv;
  if (t2 < 32) {
    float s = 0.0f;
    #pragma unroll
    for (int k = 0; k < 16; ++k) s += aux[(size_t)ids[c][k]*32 + t2];
    out[OFF_AUX + (size_t)cl*32 + t2] = s * (1.0f/16.0f);
  }
}

extern "C" void kernel_launch(void* const* d_in, const int* in_sizes, int n_in,
                              void* d_out, int out_size, void* d_ws, size_t ws_size,
                              hipStream_t stream)
{
  const float* x     = (const float*)d_in[0];
  const float* pos   = (const float*)d_in[1];
  // d_in[2] = batch (int32) — clouds are equal-size, derived analytically
  const float* aux   = (const float*)d_in[3];
  const float* W     = (const float*)d_in[4];
  const float* bias  = (const float*)d_in[5];
  const float* gamma = (const float*)d_in[6];
  const float* beta  = (const float*)d_in[7];
  float* out = (float*)d_out;
  char*  ws  = (char*)d_ws;
  if (ws_size < (size_t)WS_NEED) return;   // insufficient scratch: bail cleanly

  float*  h       = (float*)(ws + WS_H);
  float4* centers = (float4*)(ws + WS_CENTERS);
  int*    nn      = (int*)(ws + WS_NN);
  float*  stats   = (float*)(ws + WS_STATS);
  float*  ss      = (float*)(ws + WS_SS);

  hipMemsetAsync(stats, 0, 256*4, stream);  // BN accumulators: zero every call
  hipLaunchKernelGGL(fused_fps_gemm, dim3(NB + PTOT/64), dim3(256), 0, stream,
                     pos, centers, out, x, W, bias, h, stats);
  hipLaunchKernelGGL(bn_finalize, dim3(1),      dim3(128), 0, stream, stats, gamma, beta, ss);
  hipLaunchKernelGGL(knn_kernel,  dim3(512),    dim3(256), 0, stream, pos, centers, nn);
  hipLaunchKernelGGL(pool_kernel, dim3(NCLU/2), dim3(256), 0, stream, h, aux, nn, ss, out);
}

// Round 6
// 1564.960 us; speedup vs baseline: 3.0619x; 1.0679x over previous
//
#include <hip/hip_runtime.h>
#include <hip/hip_bf16.h>
#include <math.h>

#define NB    16
#define NPC   4096        // points per cloud
#define MPC   1024        // clusters per cloud
#define PTOT  65536
#define NCLU  16384
#define KNN_  16
#define CIN   64
#define COUT_ 128
#define CAUX_ 32

// out offsets (float elements), outputs concatenated in reference return order
#define OFF_XOUT   0
#define OFF_SUBPOS (NCLU*COUT_)               // 2097152
#define OFF_SUBB   (OFF_SUBPOS + NCLU*3)      // 2146304
#define OFF_AUX    (OFF_SUBB + NCLU)          // 2162688
#define OFF_IDCL   (OFF_AUX + NCLU*CAUX_)     // 2686976

// ws offsets (bytes)
#define WS_H        0
#define WS_CENTERS  (PTOT*COUT_*4)            // 33554432  (h: P x 128 f32)
#define WS_STATS    (WS_CENTERS + NCLU*16)    // centers: float4 per cluster
#define WS_SS       (WS_STATS + 256*4)
#define WS_NEED     (WS_SS + 256*4)

// ---- shared-memory overlay for the fused fps/gemm kernel -------------------
// fps view: cand is parity-double-buffered, stride 18 u64 (2-way banks only)
#define CAND_STRIDE 18
#define CAND_HALF   (16*CAND_STRIDE)    // 288 u64 per parity half
#define SM_LX    0                      // 4096 f  (16384 B)
#define SM_LY    16384
#define SM_LZ    32768
#define SM_CAND  49152                  // 2 * 288 u64 = 4608 B
#define SM_CST   53760                  // 1024 float4 (16384 B) -> 70144
// gemm view:
#define SM_XT    0                      // float[64][68] = 17408 B
#define SM_WL    17408                  // float[64][128] = 32768 B -> 50176
#define SM_BS    50176                  // float[128]
#define SM_BQ    50688                  // float[128] -> 51200
#define SM_SIZE  70144

typedef unsigned long long ull;

__device__ __forceinline__ ull packkey(float d, int jg) {
  // d >= 0 so raw float bits sort monotonically; larger (4095-jg) == smaller jg.
  return ((ull)__float_as_uint(d) << 32) | (unsigned)(4095 - jg);
}
__device__ __forceinline__ ull umax(ull a, ull b) { return a > b ? a : b; }

// tree-reduce 16 u64 keys starting at p (LDS), via 8 pipelined b128 reads
__device__ __forceinline__ ull tree16(const ull* p) {
  const ulonglong2* q = (const ulonglong2*)p;
  ulonglong2 q0 = q[0], q1 = q[1], q2 = q[2], q3 = q[3];
  ulonglong2 q4 = q[4], q5 = q[5], q6 = q[6], q7 = q[7];
  ull a = umax(umax(umax(q0.x, q0.y), umax(q1.x, q1.y)),
               umax(umax(q2.x, q2.y), umax(q3.x, q3.y)));
  ull b = umax(umax(umax(q4.x, q4.y), umax(q5.x, q5.y)),
               umax(umax(q6.x, q6.y), umax(q7.x, q7.y)));
  return umax(a, b);
}

// ---------------- FPS block: 1 barrier + 1 LDS round-trip per step ----------
__device__ void fps_block(char* smem, const float* __restrict__ pos,
                          float4* __restrict__ centers, float* __restrict__ out)
{
  #pragma clang fp contract(off)
  float* lx = (float*)(smem + SM_LX);
  float* ly = (float*)(smem + SM_LY);
  float* lz = (float*)(smem + SM_LZ);
  ull*   cand = (ull*)(smem + SM_CAND);
  float4* cst = (float4*)(smem + SM_CST);
  const int b = blockIdx.x;
  const int t = threadIdx.x;
  const float* pb = pos + (size_t)b * NPC * 3;
  const int myslot = (t >> 4) * CAND_STRIDE + (t & 15);  // slice (t>>4), elem (t&15)
  const int rdbase = (t & 15) * CAND_STRIDE;             // slice this thread reduces

  // Each thread owns 16 consecutive points (in-cloud idx t*16 .. t*16+15).
  float px[16], py[16], pz[16], mind[16];
  {
    const float4* src = (const float4*)(pb + t * 48);
    float4 v[12];
    #pragma unroll
    for (int i = 0; i < 12; ++i) v[i] = src[i];
    const float* f = (const float*)v;
    #pragma unroll
    for (int j = 0; j < 16; ++j) {
      px[j] = f[3*j]; py[j] = f[3*j+1]; pz[j] = f[3*j+2];
      lx[t*16+j] = px[j]; ly[t*16+j] = py[j]; lz[t*16+j] = pz[j];
    }
  }
  __syncthreads();
  const float x0 = lx[0], y0 = ly[0], z0 = lz[0];
  if (t == 0) cst[0] = make_float4(x0, y0, z0, __int_as_float(0));

  // initial distances to point 0 + per-thread best key
  ull bk;
  {
    ull k8[8];
    #pragma unroll
    for (int jp = 0; jp < 8; ++jp) {
      const int j0 = 2*jp, j1 = 2*jp + 1;
      float dx0 = px[j0]-x0, dy0 = py[j0]-y0, dz0 = pz[j0]-z0;
      float dx1 = px[j1]-x0, dy1 = py[j1]-y0, dz1 = pz[j1]-z0;
      float d0 = (dx0*dx0 + dy0*dy0) + dz0*dz0;   // no-FMA: matches numpy
      float d1 = (dx1*dx1 + dy1*dy1) + dz1*dz1;
      mind[j0] = d0; mind[j1] = d1;
      k8[jp] = umax(packkey(d0, t*16+j0), packkey(d1, t*16+j1));
    }
    ull k40 = umax(k8[0], k8[1]), k41 = umax(k8[2], k8[3]);
    ull k42 = umax(k8[4], k8[5]), k43 = umax(k8[6], k8[7]);
    bk = umax(umax(k40, k41), umax(k42, k43));
  }

  for (int s = 1; s < MPC; ++s) {
    const int ph = (s & 1) * CAND_HALF;
    cand[ph + myslot] = bk;
    __syncthreads();                       // the ONLY barrier per step
    // stage B: reduce slice (t&15); every 16-lane group holds all 16 slices
    ull w = tree16(cand + ph + rdbase);
    // in-register completion: 4-level xor shuffle over the 16-lane group
    #pragma unroll
    for (int off = 1; off <= 8; off <<= 1) {
      unsigned lo = (unsigned)w, hi = (unsigned)(w >> 32);
      unsigned olo = (unsigned)__shfl_xor((int)lo, off, 64);
      unsigned ohi = (unsigned)__shfl_xor((int)hi, off, 64);
      ull o = ((ull)ohi << 32) | (ull)olo;
      w = umax(w, o);
    }
    const int sel = 4095 - (int)(unsigned)(w & 0xFFFFFFFFull);
    const float sx = lx[sel], sy = ly[sel], sz = lz[sel];  // broadcast reads
    if (t == 0) cst[s] = make_float4(sx, sy, sz, __int_as_float(sel));
    // distance update + fresh per-thread best
    ull k8[8];
    #pragma unroll
    for (int jp = 0; jp < 8; ++jp) {
      const int j0 = 2*jp, j1 = 2*jp + 1;
      float dx0 = px[j0]-sx, dy0 = py[j0]-sy, dz0 = pz[j0]-sz;
      float dx1 = px[j1]-sx, dy1 = py[j1]-sy, dz1 = pz[j1]-sz;
      float d0 = (dx0*dx0 + dy0*dy0) + dz0*dz0;
      float d1 = (dx1*dx1 + dy1*dy1) + dz1*dz1;
      float m0 = fminf(mind[j0], d0), m1 = fminf(mind[j1], d1);
      mind[j0] = m0; mind[j1] = m1;
      k8[jp] = umax(packkey(m0, t*16+j0), packkey(m1, t*16+j1));
    }
    ull k40 = umax(k8[0], k8[1]), k41 = umax(k8[2], k8[3]);
    ull k42 = umax(k8[4], k8[5]), k43 = umax(k8[6], k8[7]);
    bk = umax(umax(k40, k41), umax(k42, k43));
  }
  __syncthreads();
  // coalesced output pass
  for (int c = t; c < MPC; c += 256) {
    float4 q = cst[c];
    const int il = __float_as_int(q.w);
    const int cl = b*MPC + c;
    centers[cl] = make_float4(q.x, q.y, q.z, 0.0f);
    out[OFF_SUBPOS + cl*3 + 0] = q.x;
    out[OFF_SUBPOS + cl*3 + 1] = q.y;
    out[OFF_SUBPOS + cl*3 + 2] = q.z;
    out[OFF_SUBB + cl] = (float)b;
    out[OFF_IDCL + cl] = (float)(b*NPC + il);
  }
}

// ---------------- GEMM block: h = x@W + b, plus BN sum/sumsq ----------------
__device__ void gemm_block(char* smem, const float* __restrict__ x,
                           const float* __restrict__ W, const float* __restrict__ bias,
                           float* __restrict__ h, float* __restrict__ stats, int blk)
{
  float (*xT)[68]  = (float(*)[68])(smem + SM_XT);   // [k][row], padded
  float (*Wl)[128] = (float(*)[128])(smem + SM_WL);
  float* bsum = (float*)(smem + SM_BS);
  float* bsq  = (float*)(smem + SM_BQ);
  const int t = threadIdx.x;
  const int row0 = blk * 64;
  if (t < 128) { bsum[t] = 0.0f; bsq[t] = 0.0f; }
  #pragma unroll
  for (int i = 0; i < 16; ++i) {
    const int idx = t + i*256;
    xT[idx & 63][idx >> 6] = x[(size_t)row0*64 + idx];
  }
  #pragma unroll
  for (int i = 0; i < 32; ++i) {
    const int idx = t + i*256;
    ((float*)Wl)[idx] = W[idx];
  }
  __syncthreads();
  const int tx = t & 15, ty = t >> 4;   // 16x16 threads, 4 rows x 8 cols each
  float acc[4][8] = {};
  #pragma unroll 8
  for (int k = 0; k < 64; ++k) {
    const float4 a  = *(const float4*)&xT[k][ty*4];
    const float4 b0 = *(const float4*)&Wl[k][tx*8];
    const float4 b1 = *(const float4*)&Wl[k][tx*8+4];
    const float av[4] = {a.x, a.y, a.z, a.w};
    const float bw[8] = {b0.x,b0.y,b0.z,b0.w,b1.x,b1.y,b1.z,b1.w};
    #pragma unroll
    for (int i2 = 0; i2 < 4; ++i2)
      #pragma unroll
      for (int e = 0; e < 8; ++e)
        acc[i2][e] += av[i2] * bw[e];
  }
  const int c0 = tx*8;
  float bb[8];
  #pragma unroll
  for (int e = 0; e < 8; ++e) bb[e] = bias[c0+e];
  float s8[8] = {}, q8[8] = {};
  #pragma unroll
  for (int i2 = 0; i2 < 4; ++i2) {
    float vv[8];
    #pragma unroll
    for (int e = 0; e < 8; ++e) {
      float v = acc[i2][e] + bb[e];
      vv[e] = v; s8[e] += v; q8[e] += v*v;
    }
    const int r = row0 + ty*4 + i2;
    float4* dst = (float4*)&h[(size_t)r*128 + c0];
    dst[0] = make_float4(vv[0], vv[1], vv[2], vv[3]);
    dst[1] = make_float4(vv[4], vv[5], vv[6], vv[7]);
  }
  #pragma unroll
  for (int e = 0; e < 8; ++e) {
    atomicAdd(&bsum[c0+e], s8[e]);
    atomicAdd(&bsq[c0+e],  q8[e]);
  }
  __syncthreads();
  if (t < 128) {
    atomicAdd(&stats[t],      bsum[t]);
    atomicAdd(&stats[128+t],  bsq[t]);
  }
}

// ---------------- fused launcher kernel -------------------------------------
__global__ __launch_bounds__(256) void fused_fps_gemm(const float* __restrict__ pos,
                                                      float4* __restrict__ centers,
                                                      float* __restrict__ out,
                                                      const float* __restrict__ x,
                                                      const float* __restrict__ W,
                                                      const float* __restrict__ bias,
                                                      float* __restrict__ h,
                                                      float* __restrict__ stats)
{
  __shared__ __align__(16) char smem[SM_SIZE];
  if (blockIdx.x < NB) fps_block(smem, pos, centers, out);
  else                 gemm_block(smem, x, W, bias, h, stats, blockIdx.x - NB);
}

// ------- kNN + BN + pool fused: 512 blocks, 32 centers each -----------------
__global__ __launch_bounds__(256) void knn_pool(const float* __restrict__ pos,
                                                const float4* __restrict__ centers,
                                                const float* __restrict__ h,
                                                const float* __restrict__ aux,
                                                const float* __restrict__ stats,
                                                const float* __restrict__ gamma,
                                                const float* __restrict__ beta,
                                                float* __restrict__ out)
{
  #pragma clang fp contract(off)
  __shared__ float4 lp[NPC];        // 64KB; reused as candidate scratch after scan
  __shared__ float  scl[128], ssh[128];
  __shared__ int    fid[32][16];
  const int blk = blockIdx.x;       // 512 blocks; 32 per cloud
  const int b   = blk >> 5;
  const int c0  = (blk & 31) * 32;  // first local center of this block
  const int t   = threadIdx.x;
  const int q   = t & 7;            // subset
  const int cc  = t >> 3;           // center within block, 0..31
  // BN scale/shift (redundant per block; trivial)
  if (t < 128) {
    const float inv = 1.0f / 65536.0f;
    const float mu  = stats[t] * inv;
    const float var = stats[128+t] * inv - mu*mu;
    const float sc  = gamma[t] * rsqrtf(var + 1e-5f);
    scl[t] = sc;
    ssh[t] = beta[t] - mu*sc;
  }
  const float* pb = pos + (size_t)b * NPC * 3;
  for (int i = t; i < NPC; i += 256)
    lp[i] = make_float4(pb[3*i], pb[3*i+1], pb[3*i+2], 0.0f);
  __syncthreads();
  const int cg = b*MPC + c0 + cc;   // global cluster index
  const float4 C = centers[cg];
  float dsl[16]; int isl[16];
  #pragma unroll
  for (int k = 0; k < 16; ++k) { dsl[k] = INFINITY; isl[k] = 0x7fffffff; }
  float wv = INFINITY; int wi = 0x7fffffff; int wslot = 0;
  for (int jj = 0; jj < NPC/8; ++jj) {
    const int j = jj*8 + q;         // strictly increasing within thread
    const float4 p = lp[j];
    float dx = C.x - p.x, dy = C.y - p.y, dz = C.z - p.z;
    float d2 = (dx*dx + dy*dy) + dz*dz;   // no-FMA
    if (d2 < wv || (d2 == wv && j < wi)) {
      #pragma unroll
      for (int k = 0; k < 16; ++k) if (k == wslot) { dsl[k] = d2; isl[k] = j; }
      wv = dsl[0]; wi = isl[0]; wslot = 0;
      #pragma unroll
      for (int k = 1; k < 16; ++k)
        if (dsl[k] > wv || (dsl[k] == wv && isl[k] > wi)) { wv = dsl[k]; wi = isl[k]; wslot = k; }
    }
  }
  __syncthreads();                  // pos data no longer needed
  float* cd = (float*)lp;           // [32 centers][8 subsets][16]
  int*   ci = ((int*)lp) + 32*8*16;
  #pragma unroll
  for (int k = 0; k < 16; ++k) {
    cd[(cc*8 + q)*16 + k] = dsl[k];
    ci[(cc*8 + q)*16 + k] = isl[k];
  }
  __syncthreads();
  if (q == 0) {
    // merge 128 candidates lexicographically by (d2, idx) -> exact top-16 set
    float md[16]; int mi[16];
    #pragma unroll
    for (int k = 0; k < 16; ++k) { md[k] = INFINITY; mi[k] = 0x7fffffff; }
    float w2 = INFINITY; int w2i = 0x7fffffff; int w2s = 0;
    for (int e = 0; e < 128; ++e) {
      const float d  = cd[cc*128 + e];
      const int   id = ci[cc*128 + e];
      if (d < w2 || (d == w2 && id < w2i)) {
        #pragma unroll
        for (int k = 0; k < 16; ++k) if (k == w2s) { md[k] = d; mi[k] = id; }
        w2 = md[0]; w2i = mi[0]; w2s = 0;
        #pragma unroll
        for (int k = 1; k < 16; ++k)
          if (md[k] > w2 || (md[k] == w2 && mi[k] > w2i)) { w2 = md[k]; w2i = mi[k]; w2s = k; }
      }
    }
    #pragma unroll
    for (int k = 0; k < 16; ++k) fid[cc][k] = b*NPC + mi[k];
  }
  __syncthreads();
  // ---- pool: 16 passes, 2 clusters per pass (128 cols each) ----------------
  for (int g = 0; g < 16; ++g) {
    const int cc2 = g*2 + (t >> 7);        // 0..31
    const int col = t & 127;
    const int cl  = b*MPC + c0 + cc2;
    const float sc = scl[col], sh = ssh[col];
    float mv = 0.0f;                       // relu >= 0, so 0 == -inf here
    #pragma unroll
    for (int k = 0; k < 16; ++k) {
      const float hv = h[(size_t)fid[cc2][k]*128 + col];
      mv = fmaxf(mv, fmaxf(sc*hv + sh, 0.0f));
    }
    out[OFF_XOUT + (size_t)cl*128 + col] = mv;
    if (col < 32) {
      float s = 0.0f;
      #pragma unroll
      for (int k = 0; k < 16; ++k) s += aux[(size_t)fid[cc2][k]*32 + col];
      out[OFF_AUX + (size_t)cl*32 + col] = s * (1.0f/16.0f);
    }
  }
}

extern "C" void kernel_launch(void* const* d_in, const int* in_sizes, int n_in,
                              void* d_out, int out_size, void* d_ws, size_t ws_size,
                              hipStream_t stream)
{
  const float* x     = (const float*)d_in[0];
  const float* pos   = (const float*)d_in[1];
  // d_in[2] = batch (int32) — clouds are equal-size, derived analytically
  const float* aux   = (const float*)d_in[3];
  const float* W     = (const float*)d_in[4];
  const float* bias  = (const float*)d_in[5];
  const float* gamma = (const float*)d_in[6];
  const float* beta  = (const float*)d_in[7];
  float* out = (float*)d_out;
  char*  ws  = (char*)d_ws;
  if (ws_size < (size_t)WS_NEED) return;   // insufficient scratch: bail cleanly

  float*  h       = (float*)(ws + WS_H);
  float4* centers = (float4*)(ws + WS_CENTERS);
  float*  stats   = (float*)(ws + WS_STATS);

  hipMemsetAsync(stats, 0, 256*4, stream);  // BN accumulators: zero every call
  hipLaunchKernelGGL(fused_fps_gemm, dim3(NB + PTOT/64), dim3(256), 0, stream,
                     pos, centers, out, x, W, bias, h, stats);
  hipLaunchKernelGGL(knn_pool, dim3(512), dim3(256), 0, stream,
                     pos, centers, h, aux, stats, gamma, beta, out);
}

// Round 7
// 943.298 us; speedup vs baseline: 5.0797x; 1.6590x over previous
//
#include <hip/hip_runtime.h>
#include <hip/hip_bf16.h>
#include <math.h>

#define NB    16
#define NPC   4096        // points per cloud
#define MPC   1024        // clusters per cloud
#define PTOT  65536
#define NCLU  16384
#define KNN_  16
#define CIN   64
#define COUT_ 128
#define CAUX_ 32

// out offsets (float elements), outputs concatenated in reference return order
#define OFF_XOUT   0
#define OFF_SUBPOS (NCLU*COUT_)               // 2097152
#define OFF_SUBB   (OFF_SUBPOS + NCLU*3)      // 2146304
#define OFF_AUX    (OFF_SUBB + NCLU)          // 2162688
#define OFF_IDCL   (OFF_AUX + NCLU*CAUX_)     // 2686976

// ws offsets (bytes)
#define WS_H        0
#define WS_CENTERS  (PTOT*COUT_*4)            // h: P x 128 f32
#define WS_STATS    (WS_CENTERS + NCLU*16)    // centers: float4 per cluster
#define WS_NEED     (WS_STATS + 256*4)

// ---- shared-memory overlay for the fused fps/gemm kernel -------------------
// fps view: cand is parity-double-buffered, stride 18 f64 (2-way banks only)
#define CAND_STRIDE 18
#define CAND_HALF   (16*CAND_STRIDE)    // 288 f64 per parity half
#define SM_LX    0                      // 4096 f  (16384 B)
#define SM_LY    16384
#define SM_LZ    32768
#define SM_CAND  49152                  // 2 * 288 f64 = 4608 B
#define SM_CST   53760                  // 1024 float4 (16384 B) -> 70144
// gemm view:
#define SM_XT    0                      // float[64][68] = 17408 B
#define SM_WL    17408                  // float[64][128] = 32768 B -> 50176
#define SM_BS    50176                  // float[128]
#define SM_BQ    50688                  // float[128] -> 51200
#define SM_SIZE  70144

// f64-packed keys: hi32 = f32 bits of d2 (>=0, finite -> positive f64, no NaN),
// lo32 = index payload. Positive doubles order exactly as their u64 bit
// patterns, and AMD never flushes f64 denormals -> v_max_f64/v_min_f64 give a
// single-instruction lexicographic compare.
__device__ __forceinline__ double dmax(double a, double b) { return __builtin_fmax(a, b); }
__device__ __forceinline__ double dmin(double a, double b) { return __builtin_fmin(a, b); }
__device__ __forceinline__ double pk(float d, int lo) {
  return __hiloint2double(__float_as_int(d), lo);
}
__device__ __forceinline__ int pk_lo(double k) {
  return (int)(unsigned)(__double_as_longlong(k) & 0xFFFFFFFFll);
}

// tree-reduce 16 f64 keys at p (LDS), via 8 pipelined b128 reads + v_max_f64
__device__ __forceinline__ double tree16d(const double* p) {
  const double2* q = (const double2*)p;
  double2 q0 = q[0], q1 = q[1], q2 = q[2], q3 = q[3];
  double2 q4 = q[4], q5 = q[5], q6 = q[6], q7 = q[7];
  double a = dmax(dmax(dmax(q0.x, q0.y), dmax(q1.x, q1.y)),
                  dmax(dmax(q2.x, q2.y), dmax(q3.x, q3.y)));
  double b = dmax(dmax(dmax(q4.x, q4.y), dmax(q5.x, q5.y)),
                  dmax(dmax(q6.x, q6.y), dmax(q7.x, q7.y)));
  return dmax(a, b);
}

// ---------------- FPS block: 1 barrier + 1 LDS round-trip per step ----------
__device__ void fps_block(char* smem, const float* __restrict__ pos,
                          float4* __restrict__ centers, float* __restrict__ out)
{
  #pragma clang fp contract(off)
  float* lx = (float*)(smem + SM_LX);
  float* ly = (float*)(smem + SM_LY);
  float* lz = (float*)(smem + SM_LZ);
  double* cand = (double*)(smem + SM_CAND);
  float4* cst = (float4*)(smem + SM_CST);
  const int b = blockIdx.x;
  const int t = threadIdx.x;
  const float* pb = pos + (size_t)b * NPC * 3;
  const int myslot = (t >> 4) * CAND_STRIDE + (t & 15);
  const int rdbase = (t & 15) * CAND_STRIDE;

  // Each thread owns 16 consecutive points (in-cloud idx t*16 .. t*16+15).
  float px[16], py[16], pz[16], mind[16];
  int lo16[16];                          // loop-invariant key low words
  {
    const float4* src = (const float4*)(pb + t * 48);
    float4 v[12];
    #pragma unroll
    for (int i = 0; i < 12; ++i) v[i] = src[i];
    const float* f = (const float*)v;
    #pragma unroll
    for (int j = 0; j < 16; ++j) {
      px[j] = f[3*j]; py[j] = f[3*j+1]; pz[j] = f[3*j+2];
      lx[t*16+j] = px[j]; ly[t*16+j] = py[j]; lz[t*16+j] = pz[j];
      lo16[j] = 4095 - (t*16 + j);       // larger lo == smaller idx
    }
  }
  __syncthreads();
  const float x0 = lx[0], y0 = ly[0], z0 = lz[0];
  if (t == 0) cst[0] = make_float4(x0, y0, z0, __int_as_float(0));

  // initial distances to point 0 + per-thread best key
  double bk;
  {
    double k8[8];
    #pragma unroll
    for (int jp = 0; jp < 8; ++jp) {
      const int j0 = 2*jp, j1 = 2*jp + 1;
      float dx0 = px[j0]-x0, dy0 = py[j0]-y0, dz0 = pz[j0]-z0;
      float dx1 = px[j1]-x0, dy1 = py[j1]-y0, dz1 = pz[j1]-z0;
      float d0 = (dx0*dx0 + dy0*dy0) + dz0*dz0;   // no-FMA: matches numpy
      float d1 = (dx1*dx1 + dy1*dy1) + dz1*dz1;
      mind[j0] = d0; mind[j1] = d1;
      k8[jp] = dmax(pk(d0, lo16[j0]), pk(d1, lo16[j1]));
    }
    double k40 = dmax(k8[0], k8[1]), k41 = dmax(k8[2], k8[3]);
    double k42 = dmax(k8[4], k8[5]), k43 = dmax(k8[6], k8[7]);
    bk = dmax(dmax(k40, k41), dmax(k42, k43));
  }

  for (int s = 1; s < MPC; ++s) {
    const int ph = (s & 1) * CAND_HALF;
    cand[ph + myslot] = bk;
    __syncthreads();                       // the ONLY barrier per step
    // every 16-lane group redundantly reduces all 16 slices
    double w = tree16d(cand + ph + rdbase);
    #pragma unroll
    for (int off = 1; off <= 8; off <<= 1)
      w = dmax(w, __shfl_xor(w, off, 64));
    const int sel = 4095 - pk_lo(w);
    const float sx = lx[sel], sy = ly[sel], sz = lz[sel];  // broadcast reads
    if (t == 0) cst[s] = make_float4(sx, sy, sz, __int_as_float(sel));
    // distance update + fresh per-thread best
    double k8[8];
    #pragma unroll
    for (int jp = 0; jp < 8; ++jp) {
      const int j0 = 2*jp, j1 = 2*jp + 1;
      float dx0 = px[j0]-sx, dy0 = py[j0]-sy, dz0 = pz[j0]-sz;
      float dx1 = px[j1]-sx, dy1 = py[j1]-sy, dz1 = pz[j1]-sz;
      float d0 = (dx0*dx0 + dy0*dy0) + dz0*dz0;
      float d1 = (dx1*dx1 + dy1*dy1) + dz1*dz1;
      float m0 = fminf(mind[j0], d0), m1 = fminf(mind[j1], d1);
      mind[j0] = m0; mind[j1] = m1;
      k8[jp] = dmax(pk(m0, lo16[j0]), pk(m1, lo16[j1]));
    }
    double k40 = dmax(k8[0], k8[1]), k41 = dmax(k8[2], k8[3]);
    double k42 = dmax(k8[4], k8[5]), k43 = dmax(k8[6], k8[7]);
    bk = dmax(dmax(k40, k41), dmax(k42, k43));
  }
  __syncthreads();
  // coalesced output pass
  for (int c = t; c < MPC; c += 256) {
    float4 q = cst[c];
    const int il = __float_as_int(q.w);
    const int cl = b*MPC + c;
    centers[cl] = make_float4(q.x, q.y, q.z, 0.0f);
    out[OFF_SUBPOS + cl*3 + 0] = q.x;
    out[OFF_SUBPOS + cl*3 + 1] = q.y;
    out[OFF_SUBPOS + cl*3 + 2] = q.z;
    out[OFF_SUBB + cl] = (float)b;
    out[OFF_IDCL + cl] = (float)(b*NPC + il);
  }
}

// ---------------- GEMM block: h = x@W + b, plus BN sum/sumsq ----------------
__device__ void gemm_block(char* smem, const float* __restrict__ x,
                           const float* __restrict__ W, const float* __restrict__ bias,
                           float* __restrict__ h, float* __restrict__ stats, int blk)
{
  float (*xT)[68]  = (float(*)[68])(smem + SM_XT);   // [k][row], padded
  float (*Wl)[128] = (float(*)[128])(smem + SM_WL);
  float* bsum = (float*)(smem + SM_BS);
  float* bsq  = (float*)(smem + SM_BQ);
  const int t = threadIdx.x;
  const int row0 = blk * 64;
  if (t < 128) { bsum[t] = 0.0f; bsq[t] = 0.0f; }
  #pragma unroll
  for (int i = 0; i < 16; ++i) {
    const int idx = t + i*256;
    xT[idx & 63][idx >> 6] = x[(size_t)row0*64 + idx];
  }
  #pragma unroll
  for (int i = 0; i < 32; ++i) {
    const int idx = t + i*256;
    ((float*)Wl)[idx] = W[idx];
  }
  __syncthreads();
  const int tx = t & 15, ty = t >> 4;   // 16x16 threads, 4 rows x 8 cols each
  float acc[4][8] = {};
  #pragma unroll 8
  for (int k = 0; k < 64; ++k) {
    const float4 a  = *(const float4*)&xT[k][ty*4];
    const float4 b0 = *(const float4*)&Wl[k][tx*8];
    const float4 b1 = *(const float4*)&Wl[k][tx*8+4];
    const float av[4] = {a.x, a.y, a.z, a.w};
    const float bw[8] = {b0.x,b0.y,b0.z,b0.w,b1.x,b1.y,b1.z,b1.w};
    #pragma unroll
    for (int i2 = 0; i2 < 4; ++i2)
      #pragma unroll
      for (int e = 0; e < 8; ++e)
        acc[i2][e] += av[i2] * bw[e];
  }
  const int c0 = tx*8;
  float bb[8];
  #pragma unroll
  for (int e = 0; e < 8; ++e) bb[e] = bias[c0+e];
  float s8[8] = {}, q8[8] = {};
  #pragma unroll
  for (int i2 = 0; i2 < 4; ++i2) {
    float vv[8];
    #pragma unroll
    for (int e = 0; e < 8; ++e) {
      float v = acc[i2][e] + bb[e];
      vv[e] = v; s8[e] += v; q8[e] += v*v;
    }
    const int r = row0 + ty*4 + i2;
    float4* dst = (float4*)&h[(size_t)r*128 + c0];
    dst[0] = make_float4(vv[0], vv[1], vv[2], vv[3]);
    dst[1] = make_float4(vv[4], vv[5], vv[6], vv[7]);
  }
  #pragma unroll
  for (int e = 0; e < 8; ++e) {
    atomicAdd(&bsum[c0+e], s8[e]);
    atomicAdd(&bsq[c0+e],  q8[e]);
  }
  __syncthreads();
  if (t < 128) {
    atomicAdd(&stats[t],      bsum[t]);
    atomicAdd(&stats[128+t],  bsq[t]);
  }
}

// ---------------- fused launcher kernel -------------------------------------
__global__ __launch_bounds__(256) void fused_fps_gemm(const float* __restrict__ pos,
                                                      float4* __restrict__ centers,
                                                      float* __restrict__ out,
                                                      const float* __restrict__ x,
                                                      const float* __restrict__ W,
                                                      const float* __restrict__ bias,
                                                      float* __restrict__ h,
                                                      float* __restrict__ stats)
{
  __shared__ __align__(16) char smem[SM_SIZE];
  if (blockIdx.x < NB) fps_block(smem, pos, centers, out);
  else                 gemm_block(smem, x, W, bias, h, stats, blockIdx.x - NB);
}

// ------- kNN + BN + pool fused: 512 blocks, 32 centers each -----------------
// kNN keys: f64 pack (d2 bits, idx); MIN key == lex (d2 asc, idx asc).
// Per-lane sorted-descending list L[0..15] (L[0] = worst): insert is 31 f64
// min/max ops, no rescan. Neighbor order within the 16 is irrelevant (only
// max/mean pooling consumes it).
#define KBIG __hiloint2double(0x7f7fffff, 0xffffffff)
#define KNEG (-__hiloint2double(0x7f7fffff, 0xffffffff))
#define CD_STRIDE 17                     // pad: kill 32-way write conflicts

__global__ __launch_bounds__(256) void knn_pool(const float* __restrict__ pos,
                                                const float4* __restrict__ centers,
                                                const float* __restrict__ h,
                                                const float* __restrict__ aux,
                                                const float* __restrict__ stats,
                                                const float* __restrict__ gamma,
                                                const float* __restrict__ beta,
                                                float* __restrict__ out)
{
  #pragma clang fp contract(off)
  __shared__ float4 lp[NPC];        // 64KB; reused as candidate scratch after scan
  __shared__ float  scl[128], ssh[128];
  __shared__ int    fid[32][16];
  const int blk = blockIdx.x;       // 512 blocks; 32 per cloud
  const int b   = blk >> 5;
  const int c0  = (blk & 31) * 32;  // first local center of this block
  const int t   = threadIdx.x;
  const int q   = t & 7;            // subset
  const int cc  = t >> 3;           // center within block, 0..31
  // BN scale/shift (redundant per block; trivial)
  if (t < 128) {
    const float inv = 1.0f / 65536.0f;
    const float mu  = stats[t] * inv;
    const float var = stats[128+t] * inv - mu*mu;
    const float sc  = gamma[t] * rsqrtf(var + 1e-5f);
    scl[t] = sc;
    ssh[t] = beta[t] - mu*sc;
  }
  const float* pb = pos + (size_t)b * NPC * 3;
  for (int i = t; i < NPC; i += 256)
    lp[i] = make_float4(pb[3*i], pb[3*i+1], pb[3*i+2], 0.0f);
  __syncthreads();
  const int cg = b*MPC + c0 + cc;   // global cluster index
  const float4 C = centers[cg];
  double L[16];
  #pragma unroll
  for (int k = 0; k < 16; ++k) L[k] = KBIG;
  for (int jj = 0; jj < NPC/8; ++jj) {
    const int j = jj*8 + q;
    const float4 p = lp[j];
    float dx = C.x - p.x, dy = C.y - p.y, dz = C.z - p.z;
    float d2 = (dx*dx + dy*dy) + dz*dz;   // no-FMA
    double nk = pk(d2, j);
    if (nk < L[0]) {                      // beats current worst -> sorted insert
      #pragma unroll
      for (int k = 0; k < 15; ++k) L[k] = dmin(L[k], dmax(L[k+1], nk));
      L[15] = dmin(L[15], nk);
    }
  }
  __syncthreads();                  // pos data no longer needed
  double* cd = (double*)lp;         // [256 lanes][17-padded 16 keys] = 34816 B
  #pragma unroll
  for (int k = 0; k < 16; ++k) cd[t*CD_STRIDE + k] = L[k];
  __syncthreads();
  if (q == 0) {
    // merge 8 sorted sublists (128 keys) -> exact global top-16 set
    double M[16];
    #pragma unroll
    for (int k = 0; k < 16; ++k) M[k] = KBIG;
    for (int ss = 0; ss < 8; ++ss) {
      const double* src = cd + (cc*8 + ss)*CD_STRIDE;
      #pragma unroll
      for (int k = 0; k < 16; ++k) {
        double nk = src[k];
        if (nk < M[0]) {
          #pragma unroll
          for (int m = 0; m < 15; ++m) M[m] = dmin(M[m], dmax(M[m+1], nk));
          M[15] = dmin(M[15], nk);
        }
      }
    }
    #pragma unroll
    for (int k = 0; k < 16; ++k) fid[cc][k] = b*NPC + pk_lo(M[k]);
  }
  __syncthreads();
  // ---- pool: 16 passes, 2 clusters per pass (128 cols each) ----------------
  for (int g = 0; g < 16; ++g) {
    const int cc2 = g*2 + (t >> 7);        // 0..31
    const int col = t & 127;
    const int cl  = b*MPC + c0 + cc2;
    const float sc = scl[col], sh = ssh[col];
    float mv = 0.0f;                       // relu >= 0, so 0 == -inf here
    #pragma unroll
    for (int k = 0; k < 16; ++k) {
      const float hv = h[(size_t)fid[cc2][k]*128 + col];
      mv = fmaxf(mv, fmaxf(sc*hv + sh, 0.0f));
    }
    out[OFF_XOUT + (size_t)cl*128 + col] = mv;
    if (col < 32) {
      float s = 0.0f;
      #pragma unroll
      for (int k = 0; k < 16; ++k) s += aux[(size_t)fid[cc2][k]*32 + col];
      out[OFF_AUX + (size_t)cl*32 + col] = s * (1.0f/16.0f);
    }
  }
}

extern "C" void kernel_launch(void* const* d_in, const int* in_sizes, int n_in,
                              void* d_out, int out_size, void* d_ws, size_t ws_size,
                              hipStream_t stream)
{
  const float* x     = (const float*)d_in[0];
  const float* pos   = (const float*)d_in[1];
  // d_in[2] = batch (int32) — clouds are equal-size, derived analytically
  const float* aux   = (const float*)d_in[3];
  const float* W     = (const float*)d_in[4];
  const float* bias  = (const float*)d_in[5];
  const float* gamma = (const float*)d_in[6];
  const float* beta  = (const float*)d_in[7];
  float* out = (float*)d_out;
  char*  ws  = (char*)d_ws;
  if (ws_size < (size_t)WS_NEED) return;   // insufficient scratch: bail cleanly

  float*  h       = (float*)(ws + WS_H);
  float4* centers = (float4*)(ws + WS_CENTERS);
  float*  stats   = (float*)(ws + WS_STATS);

  hipMemsetAsync(stats, 0, 256*4, stream);  // BN accumulators: zero every call
  hipLaunchKernelGGL(fused_fps_gemm, dim3(NB + PTOT/64), dim3(256), 0, stream,
                     pos, centers, out, x, W, bias, h, stats);
  hipLaunchKernelGGL(knn_pool, dim3(512), dim3(256), 0, stream,
                     pos, centers, h, aux, stats, gamma, beta, out);
}

// Round 8
// 828.782 us; speedup vs baseline: 5.7816x; 1.1382x over previous
//
#include <hip/hip_runtime.h>
#include <hip/hip_bf16.h>
#include <math.h>

#define NB    16
#define NPC   4096        // points per cloud
#define MPC   1024        // clusters per cloud
#define PTOT  65536
#define NCLU  16384
#define KNN_  16
#define CIN   64
#define COUT_ 128
#define CAUX_ 32

// out offsets (float elements), outputs concatenated in reference return order
#define OFF_XOUT   0
#define OFF_SUBPOS (NCLU*COUT_)               // 2097152
#define OFF_SUBB   (OFF_SUBPOS + NCLU*3)      // 2146304
#define OFF_AUX    (OFF_SUBB + NCLU)          // 2162688
#define OFF_IDCL   (OFF_AUX + NCLU*CAUX_)     // 2686976

// ws offsets (bytes)
#define WS_H        0
#define WS_CENTERS  (PTOT*COUT_*4)            // h: P x 128 f32
#define WS_STATS    (WS_CENTERS + NCLU*16)    // centers: float4 per cluster
#define WS_NEED     (WS_STATS + 256*4)

// ---- shared-memory overlay for the fused fps/gemm kernel -------------------
// fps view: cand is parity-double-buffered, stride 18 f64 (2-way banks only)
#define CAND_STRIDE 18
#define CAND_HALF   (16*CAND_STRIDE)    // 288 f64 per parity half
#define SM_LX    0                      // 4096 f  (16384 B)
#define SM_LY    16384
#define SM_LZ    32768
#define SM_CAND  49152                  // 2 * 288 f64 = 4608 B
#define SM_CST   53760                  // 1024 float4 (16384 B) -> 70144
// gemm view:
#define SM_XT    0                      // float[64][68] = 17408 B
#define SM_WL    17408                  // float[64][128] = 32768 B -> 50176
#define SM_BS    50176                  // float[128]
#define SM_BQ    50688                  // float[128] -> 51200
#define SM_SIZE  70144

// f64-packed keys: hi32 = f32 bits of d2 (>=0, finite -> positive f64, no NaN),
// lo32 = index payload. Positive doubles order exactly as their u64 bit
// patterns, and AMD never flushes f64 denormals -> v_max_f64/v_min_f64 give a
// single-instruction lexicographic compare.
__device__ __forceinline__ double dmax(double a, double b) { return __builtin_fmax(a, b); }
__device__ __forceinline__ double dmin(double a, double b) { return __builtin_fmin(a, b); }
__device__ __forceinline__ double pk(float d, int lo) {
  return __hiloint2double(__float_as_int(d), lo);
}
__device__ __forceinline__ int pk_lo(double k) {
  return (int)(unsigned)(__double_as_longlong(k) & 0xFFFFFFFFll);
}

// DPP row_ror:N on an f64 (both 32b halves, same control -> consistent lanes).
// VALU pipe: ~10cy/level vs ~130cy/level for ds_bpermute-based __shfl_xor.
template <int CTRL>
__device__ __forceinline__ double dpp64(double v) {
  long long u = __double_as_longlong(v);
  int lo = (int)(unsigned)(u & 0xFFFFFFFFll);
  int hi = (int)(unsigned)((unsigned long long)u >> 32);
  int rlo = __builtin_amdgcn_update_dpp(0, lo, CTRL, 0xf, 0xf, true);
  int rhi = __builtin_amdgcn_update_dpp(0, hi, CTRL, 0xf, 0xf, true);
  return __longlong_as_double(((long long)rhi << 32) | (long long)(unsigned)rlo);
}
#define ROR1 0x121
#define ROR2 0x122
#define ROR4 0x124
#define ROR8 0x128

// tree-reduce 16 f64 keys at p (LDS), via 8 pipelined b128 reads + v_max_f64
__device__ __forceinline__ double tree16d(const double* p) {
  const double2* q = (const double2*)p;
  double2 q0 = q[0], q1 = q[1], q2 = q[2], q3 = q[3];
  double2 q4 = q[4], q5 = q[5], q6 = q[6], q7 = q[7];
  double a = dmax(dmax(dmax(q0.x, q0.y), dmax(q1.x, q1.y)),
                  dmax(dmax(q2.x, q2.y), dmax(q3.x, q3.y)));
  double b = dmax(dmax(dmax(q4.x, q4.y), dmax(q5.x, q5.y)),
                  dmax(dmax(q6.x, q6.y), dmax(q7.x, q7.y)));
  return dmax(a, b);
}

// ---------------- FPS block: 1 barrier + 1 LDS round-trip per step ----------
__device__ void fps_block(char* smem, const float* __restrict__ pos,
                          float4* __restrict__ centers, float* __restrict__ out)
{
  #pragma clang fp contract(off)
  float* lx = (float*)(smem + SM_LX);
  float* ly = (float*)(smem + SM_LY);
  float* lz = (float*)(smem + SM_LZ);
  double* cand = (double*)(smem + SM_CAND);
  float4* cst = (float4*)(smem + SM_CST);
  const int b = blockIdx.x;
  const int t = threadIdx.x;
  const float* pb = pos + (size_t)b * NPC * 3;
  const int myslot = (t >> 4) * CAND_STRIDE + (t & 15);
  const int rdbase = (t & 15) * CAND_STRIDE;

  // Each thread owns 16 consecutive points (in-cloud idx t*16 .. t*16+15).
  float px[16], py[16], pz[16], mind[16];
  int lo16[16];                          // loop-invariant key low words
  {
    const float4* src = (const float4*)(pb + t * 48);
    float4 v[12];
    #pragma unroll
    for (int i = 0; i < 12; ++i) v[i] = src[i];
    const float* f = (const float*)v;
    #pragma unroll
    for (int j = 0; j < 16; ++j) {
      px[j] = f[3*j]; py[j] = f[3*j+1]; pz[j] = f[3*j+2];
      lx[t*16+j] = px[j]; ly[t*16+j] = py[j]; lz[t*16+j] = pz[j];
      lo16[j] = 4095 - (t*16 + j);       // larger lo == smaller idx
    }
  }
  __syncthreads();
  const float x0 = lx[0], y0 = ly[0], z0 = lz[0];
  if (t == 0) cst[0] = make_float4(x0, y0, z0, __int_as_float(0));

  // initial distances to point 0 + per-thread best key
  double bk;
  {
    double k8[8];
    #pragma unroll
    for (int jp = 0; jp < 8; ++jp) {
      const int j0 = 2*jp, j1 = 2*jp + 1;
      float dx0 = px[j0]-x0, dy0 = py[j0]-y0, dz0 = pz[j0]-z0;
      float dx1 = px[j1]-x0, dy1 = py[j1]-y0, dz1 = pz[j1]-z0;
      float d0 = (dx0*dx0 + dy0*dy0) + dz0*dz0;   // no-FMA: matches numpy
      float d1 = (dx1*dx1 + dy1*dy1) + dz1*dz1;
      mind[j0] = d0; mind[j1] = d1;
      k8[jp] = dmax(pk(d0, lo16[j0]), pk(d1, lo16[j1]));
    }
    double k40 = dmax(k8[0], k8[1]), k41 = dmax(k8[2], k8[3]);
    double k42 = dmax(k8[4], k8[5]), k43 = dmax(k8[6], k8[7]);
    bk = dmax(dmax(k40, k41), dmax(k42, k43));
  }

  for (int s = 1; s < MPC; ++s) {
    const int ph = (s & 1) * CAND_HALF;
    cand[ph + myslot] = bk;
    __syncthreads();                       // the ONLY barrier per step
    // every 16-lane group redundantly reduces all 16 slices
    double w = tree16d(cand + ph + rdbase);
    // complete across the 16-lane row on the VALU pipe (DPP rotate-accumulate)
    w = dmax(w, dpp64<ROR1>(w));
    w = dmax(w, dpp64<ROR2>(w));
    w = dmax(w, dpp64<ROR4>(w));
    w = dmax(w, dpp64<ROR8>(w));
    const int sel = 4095 - pk_lo(w);
    const float sx = lx[sel], sy = ly[sel], sz = lz[sel];  // broadcast reads
    if (t == 0) cst[s] = make_float4(sx, sy, sz, __int_as_float(sel));
    // distance update + fresh per-thread best
    double k8[8];
    #pragma unroll
    for (int jp = 0; jp < 8; ++jp) {
      const int j0 = 2*jp, j1 = 2*jp + 1;
      float dx0 = px[j0]-sx, dy0 = py[j0]-sy, dz0 = pz[j0]-sz;
      float dx1 = px[j1]-sx, dy1 = py[j1]-sy, dz1 = pz[j1]-sz;
      float d0 = (dx0*dx0 + dy0*dy0) + dz0*dz0;
      float d1 = (dx1*dx1 + dy1*dy1) + dz1*dz1;
      float m0 = fminf(mind[j0], d0), m1 = fminf(mind[j1], d1);
      mind[j0] = m0; mind[j1] = m1;
      k8[jp] = dmax(pk(m0, lo16[j0]), pk(m1, lo16[j1]));
    }
    double k40 = dmax(k8[0], k8[1]), k41 = dmax(k8[2], k8[3]);
    double k42 = dmax(k8[4], k8[5]), k43 = dmax(k8[6], k8[7]);
    bk = dmax(dmax(k40, k41), dmax(k42, k43));
  }
  __syncthreads();
  // coalesced output pass
  for (int c = t; c < MPC; c += 256) {
    float4 q = cst[c];
    const int il = __float_as_int(q.w);
    const int cl = b*MPC + c;
    centers[cl] = make_float4(q.x, q.y, q.z, 0.0f);
    out[OFF_SUBPOS + cl*3 + 0] = q.x;
    out[OFF_SUBPOS + cl*3 + 1] = q.y;
    out[OFF_SUBPOS + cl*3 + 2] = q.z;
    out[OFF_SUBB + cl] = (float)b;
    out[OFF_IDCL + cl] = (float)(b*NPC + il);
  }
}

// ---------------- GEMM block: h = x@W + b, plus BN sum/sumsq ----------------
__device__ void gemm_block(char* smem, const float* __restrict__ x,
                           const float* __restrict__ W, const float* __restrict__ bias,
                           float* __restrict__ h, float* __restrict__ stats, int blk)
{
  float (*xT)[68]  = (float(*)[68])(smem + SM_XT);   // [k][row], padded
  float (*Wl)[128] = (float(*)[128])(smem + SM_WL);
  float* bsum = (float*)(smem + SM_BS);
  float* bsq  = (float*)(smem + SM_BQ);
  const int t = threadIdx.x;
  const int row0 = blk * 64;
  if (t < 128) { bsum[t] = 0.0f; bsq[t] = 0.0f; }
  #pragma unroll
  for (int i = 0; i < 16; ++i) {
    const int idx = t + i*256;
    xT[idx & 63][idx >> 6] = x[(size_t)row0*64 + idx];
  }
  #pragma unroll
  for (int i = 0; i < 32; ++i) {
    const int idx = t + i*256;
    ((float*)Wl)[idx] = W[idx];
  }
  __syncthreads();
  const int tx = t & 15, ty = t >> 4;   // 16x16 threads, 4 rows x 8 cols each
  float acc[4][8] = {};
  #pragma unroll 8
  for (int k = 0; k < 64; ++k) {
    const float4 a  = *(const float4*)&xT[k][ty*4];
    const float4 b0 = *(const float4*)&Wl[k][tx*8];
    const float4 b1 = *(const float4*)&Wl[k][tx*8+4];
    const float av[4] = {a.x, a.y, a.z, a.w};
    const float bw[8] = {b0.x,b0.y,b0.z,b0.w,b1.x,b1.y,b1.z,b1.w};
    #pragma unroll
    for (int i2 = 0; i2 < 4; ++i2)
      #pragma unroll
      for (int e = 0; e < 8; ++e)
        acc[i2][e] += av[i2] * bw[e];
  }
  const int c0 = tx*8;
  float bb[8];
  #pragma unroll
  for (int e = 0; e < 8; ++e) bb[e] = bias[c0+e];
  float s8[8] = {}, q8[8] = {};
  #pragma unroll
  for (int i2 = 0; i2 < 4; ++i2) {
    float vv[8];
    #pragma unroll
    for (int e = 0; e < 8; ++e) {
      float v = acc[i2][e] + bb[e];
      vv[e] = v; s8[e] += v; q8[e] += v*v;
    }
    const int r = row0 + ty*4 + i2;
    float4* dst = (float4*)&h[(size_t)r*128 + c0];
    dst[0] = make_float4(vv[0], vv[1], vv[2], vv[3]);
    dst[1] = make_float4(vv[4], vv[5], vv[6], vv[7]);
  }
  #pragma unroll
  for (int e = 0; e < 8; ++e) {
    atomicAdd(&bsum[c0+e], s8[e]);
    atomicAdd(&bsq[c0+e],  q8[e]);
  }
  __syncthreads();
  if (t < 128) {
    atomicAdd(&stats[t],      bsum[t]);
    atomicAdd(&stats[128+t],  bsq[t]);
  }
}

// ---------------- fused launcher kernel -------------------------------------
__global__ __launch_bounds__(256) void fused_fps_gemm(const float* __restrict__ pos,
                                                      float4* __restrict__ centers,
                                                      float* __restrict__ out,
                                                      const float* __restrict__ x,
                                                      const float* __restrict__ W,
                                                      const float* __restrict__ bias,
                                                      float* __restrict__ h,
                                                      float* __restrict__ stats)
{
  __shared__ __align__(16) char smem[SM_SIZE];
  if (blockIdx.x < NB) fps_block(smem, pos, centers, out);
  else                 gemm_block(smem, x, W, bias, h, stats, blockIdx.x - NB);
}

// ------- kNN + BN + pool fused: 512 blocks, 32 centers each -----------------
// kNN keys: f64 pack (d2 bits, idx); MIN key == lex (d2 asc, idx asc).
// Per-lane sorted-descending list L[0..15] (L[0] = worst): insert is 31 f64
// min/max ops, no rescan. Neighbor order within the 16 is irrelevant (only
// max/mean pooling consumes it).
#define KBIG __hiloint2double(0x7f7fffff, 0xffffffff)
#define CD_STRIDE 17                     // pad: kill 32-way write conflicts

__global__ __launch_bounds__(256) void knn_pool(const float* __restrict__ pos,
                                                const float4* __restrict__ centers,
                                                const float* __restrict__ h,
                                                const float* __restrict__ aux,
                                                const float* __restrict__ stats,
                                                const float* __restrict__ gamma,
                                                const float* __restrict__ beta,
                                                float* __restrict__ out)
{
  #pragma clang fp contract(off)
  __shared__ float4 lp[NPC];        // 64KB; reused as candidate scratch after scan
  __shared__ float  scl[128], ssh[128];
  __shared__ int    fid[32][16];
  const int blk = blockIdx.x;       // 512 blocks; 32 per cloud
  const int b   = blk >> 5;
  const int c0  = (blk & 31) * 32;  // first local center of this block
  const int t   = threadIdx.x;
  const int q   = t & 7;            // subset
  const int cc  = t >> 3;           // center within block, 0..31
  // BN scale/shift (redundant per block; trivial)
  if (t < 128) {
    const float inv = 1.0f / 65536.0f;
    const float mu  = stats[t] * inv;
    const float var = stats[128+t] * inv - mu*mu;
    const float sc  = gamma[t] * rsqrtf(var + 1e-5f);
    scl[t] = sc;
    ssh[t] = beta[t] - mu*sc;
  }
  const float* pb = pos + (size_t)b * NPC * 3;
  for (int i = t; i < NPC; i += 256)
    lp[i] = make_float4(pb[3*i], pb[3*i+1], pb[3*i+2], 0.0f);
  __syncthreads();
  const int cg = b*MPC + c0 + cc;   // global cluster index
  const float4 C = centers[cg];
  double L[16];
  #pragma unroll
  for (int k = 0; k < 16; ++k) L[k] = KBIG;
  for (int jj = 0; jj < NPC/8; ++jj) {
    const int j = jj*8 + q;
    const float4 p = lp[j];
    float dx = C.x - p.x, dy = C.y - p.y, dz = C.z - p.z;
    float d2 = (dx*dx + dy*dy) + dz*dz;   // no-FMA
    double nk = pk(d2, j);
    if (nk < L[0]) {                      // beats current worst -> sorted insert
      #pragma unroll
      for (int k = 0; k < 15; ++k) L[k] = dmin(L[k], dmax(L[k+1], nk));
      L[15] = dmin(L[15], nk);
    }
  }
  __syncthreads();                  // pos data no longer needed
  double* cd = (double*)lp;         // [256 lanes][17-padded 16 keys] = 34816 B
  #pragma unroll
  for (int k = 0; k < 16; ++k) cd[t*CD_STRIDE + k] = L[k];
  __syncthreads();
  if (q == 0) {
    // merge 8 sorted sublists (128 keys) -> exact global top-16 set
    double M[16];
    #pragma unroll
    for (int k = 0; k < 16; ++k) M[k] = KBIG;
    for (int ss = 0; ss < 8; ++ss) {
      const double* src = cd + (cc*8 + ss)*CD_STRIDE;
      #pragma unroll
      for (int k = 0; k < 16; ++k) {
        double nk = src[k];
        if (nk < M[0]) {
          #pragma unroll
          for (int m = 0; m < 15; ++m) M[m] = dmin(M[m], dmax(M[m+1], nk));
          M[15] = dmin(M[15], nk);
        }
      }
    }
    #pragma unroll
    for (int k = 0; k < 16; ++k) fid[cc][k] = b*NPC + pk_lo(M[k]);
  }
  __syncthreads();
  // ---- pool: 16 passes, 2 clusters per pass (128 cols each) ----------------
  for (int g = 0; g < 16; ++g) {
    const int cc2 = g*2 + (t >> 7);        // 0..31
    const int col = t & 127;
    const int cl  = b*MPC + c0 + cc2;
    const float sc = scl[col], sh = ssh[col];
    float mv = 0.0f;                       // relu >= 0, so 0 == -inf here
    #pragma unroll
    for (int k = 0; k < 16; ++k) {
      const float hv = h[(size_t)fid[cc2][k]*128 + col];
      mv = fmaxf(mv, fmaxf(sc*hv + sh, 0.0f));
    }
    out[OFF_XOUT + (size_t)cl*128 + col] = mv;
    if (col < 32) {
      float s = 0.0f;
      #pragma unroll
      for (int k = 0; k < 16; ++k) s += aux[(size_t)fid[cc2][k]*32 + col];
      out[OFF_AUX + (size_t)cl*32 + col] = s * (1.0f/16.0f);
    }
  }
}

extern "C" void kernel_launch(void* const* d_in, const int* in_sizes, int n_in,
                              void* d_out, int out_size, void* d_ws, size_t ws_size,
                              hipStream_t stream)
{
  const float* x     = (const float*)d_in[0];
  const float* pos   = (const float*)d_in[1];
  // d_in[2] = batch (int32) — clouds are equal-size, derived analytically
  const float* aux   = (const float*)d_in[3];
  const float* W     = (const float*)d_in[4];
  const float* bias  = (const float*)d_in[5];
  const float* gamma = (const float*)d_in[6];
  const float* beta  = (const float*)d_in[7];
  float* out = (float*)d_out;
  char*  ws  = (char*)d_ws;
  if (ws_size < (size_t)WS_NEED) return;   // insufficient scratch: bail cleanly

  float*  h       = (float*)(ws + WS_H);
  float4* centers = (float4*)(ws + WS_CENTERS);
  float*  stats   = (float*)(ws + WS_STATS);

  hipMemsetAsync(stats, 0, 256*4, stream);  // BN accumulators: zero every call
  hipLaunchKernelGGL(fused_fps_gemm, dim3(NB + PTOT/64), dim3(256), 0, stream,
                     pos, centers, out, x, W, bias, h, stats);
  hipLaunchKernelGGL(knn_pool, dim3(512), dim3(256), 0, stream,
                     pos, centers, h, aux, stats, gamma, beta, out);
}

// Round 9
// 762.213 us; speedup vs baseline: 6.2866x; 1.0873x over previous
//
#include <hip/hip_runtime.h>
#include <hip/hip_bf16.h>
#include <math.h>

#define NB    16
#define NPC   4096        // points per cloud
#define MPC   1024        // clusters per cloud
#define PTOT  65536
#define NCLU  16384
#define KNN_  16
#define CIN   64
#define COUT_ 128
#define CAUX_ 32

// out offsets (float elements), outputs concatenated in reference return order
#define OFF_XOUT   0
#define OFF_SUBPOS (NCLU*COUT_)               // 2097152
#define OFF_SUBB   (OFF_SUBPOS + NCLU*3)      // 2146304
#define OFF_AUX    (OFF_SUBB + NCLU)          // 2162688
#define OFF_IDCL   (OFF_AUX + NCLU*CAUX_)     // 2686976

// ws offsets (bytes)
#define WS_H        0
#define WS_CENTERS  (PTOT*COUT_*4)            // h: P x 128 f32
#define WS_STATS    (WS_CENTERS + NCLU*16)    // centers: float4 per cluster
#define WS_NEED     (WS_STATS + 256*4)

// ---- shared-memory overlay for the fused fps/gemm kernel (512 threads) -----
// fps view: cand = 2 parity halves x 32 f64 (one entry per 16-lane row)
#define SM_LX    0                      // 4096 f  (16384 B)
#define SM_LY    16384
#define SM_LZ    32768
#define SM_CAND  49152                  // 2 * 32 f64 = 512 B
#define SM_CSEL  49664                  // 1024 int = 4096 B -> 53760
// gemm view:
#define SM_XT    0                      // float[64][68] = 17408 B
#define SM_WL    17408                  // float[64][128] = 32768 B -> 50176
#define SM_BS    50176                  // float[128]
#define SM_BQ    50688                  // float[128] -> 51200
#define SM_SIZE  53760

// f64-packed keys: hi32 = f32 bits of d2 (>=0, finite -> positive f64, no NaN),
// lo32 = index payload. Positive doubles order exactly as their u64 bit
// patterns; f64 denormals are never flushed on AMD -> v_max_f64/v_min_f64 is a
// single-instruction lexicographic compare.
__device__ __forceinline__ double dmax(double a, double b) { return __builtin_fmax(a, b); }
__device__ __forceinline__ double dmin(double a, double b) { return __builtin_fmin(a, b); }
__device__ __forceinline__ double pk(float d, int lo) {
  return __hiloint2double(__float_as_int(d), lo);
}
__device__ __forceinline__ int pk_lo(double k) {
  return (int)(unsigned)(__double_as_longlong(k) & 0xFFFFFFFFll);
}

// DPP row_ror:N on an f64 (both 32b halves, same control -> consistent lanes).
template <int CTRL>
__device__ __forceinline__ double dpp64(double v) {
  long long u = __double_as_longlong(v);
  int lo = (int)(unsigned)(u & 0xFFFFFFFFll);
  int hi = (int)(unsigned)((unsigned long long)u >> 32);
  int rlo = __builtin_amdgcn_update_dpp(0, lo, CTRL, 0xf, 0xf, true);
  int rhi = __builtin_amdgcn_update_dpp(0, hi, CTRL, 0xf, 0xf, true);
  return __longlong_as_double(((long long)rhi << 32) | (long long)(unsigned)rlo);
}
#define ROR1 0x121
#define ROR2 0x122
#define ROR4 0x124
#define ROR8 0x128

// full 16-lane-row max via DPP rotate-accumulate (VALU pipe only)
__device__ __forceinline__ double rowmax16(double w) {
  w = dmax(w, dpp64<ROR1>(w));
  w = dmax(w, dpp64<ROR2>(w));
  w = dmax(w, dpp64<ROR4>(w));
  w = dmax(w, dpp64<ROR8>(w));
  return w;
}

// ---------------- FPS block: 512 thr, wave pre-reduce, 1 barrier/step -------
__device__ void fps_block(char* smem, const float* __restrict__ pos,
                          float4* __restrict__ centers, float* __restrict__ out)
{
  #pragma clang fp contract(off)
  float* lx = (float*)(smem + SM_LX);
  float* ly = (float*)(smem + SM_LY);
  float* lz = (float*)(smem + SM_LZ);
  double* cand = (double*)(smem + SM_CAND);
  int*   csel = (int*)(smem + SM_CSEL);
  const int b = blockIdx.x;
  const int t = threadIdx.x;
  const float* pb = pos + (size_t)b * NPC * 3;
  const int entry  = (t >> 6) * 4 + ((t >> 4) & 3);   // wid*4 + row = 0..31
  const bool writer = ((t & 15) == 0);                // lane 0 of each row

  // Each thread owns 8 consecutive points (in-cloud idx t*8 .. t*8+7).
  float px[8], py[8], pz[8], mind[8];
  int lo8[8];                            // loop-invariant key low words
  {
    const float4* src = (const float4*)(pb + t * 24);
    float4 v[6];
    #pragma unroll
    for (int i = 0; i < 6; ++i) v[i] = src[i];
    const float* f = (const float*)v;
    #pragma unroll
    for (int j = 0; j < 8; ++j) {
      px[j] = f[3*j]; py[j] = f[3*j+1]; pz[j] = f[3*j+2];
      lx[t*8+j] = px[j]; ly[t*8+j] = py[j]; lz[t*8+j] = pz[j];
      lo8[j] = 4095 - (t*8 + j);         // larger lo == smaller idx
    }
  }
  __syncthreads();
  const float x0 = lx[0], y0 = ly[0], z0 = lz[0];
  if (t == 0) csel[0] = 0;

  // initial distances to point 0 + per-thread best key
  double bk;
  {
    double k4[4];
    #pragma unroll
    for (int jp = 0; jp < 4; ++jp) {
      const int j0 = 2*jp, j1 = 2*jp + 1;
      float dx0 = px[j0]-x0, dy0 = py[j0]-y0, dz0 = pz[j0]-z0;
      float dx1 = px[j1]-x0, dy1 = py[j1]-y0, dz1 = pz[j1]-z0;
      float d0 = (dx0*dx0 + dy0*dy0) + dz0*dz0;   // no-FMA: matches numpy
      float d1 = (dx1*dx1 + dy1*dy1) + dz1*dz1;
      mind[j0] = d0; mind[j1] = d1;
      k4[jp] = dmax(pk(d0, lo8[j0]), pk(d1, lo8[j1]));
    }
    bk = dmax(dmax(k4[0], k4[1]), dmax(k4[2], k4[3]));
  }

  for (int s = 1; s < MPC; ++s) {
    // wave-level pre-reduce on VALU pipe; one f64 per 16-lane row to LDS
    double w = rowmax16(bk);
    const int ph = (s & 1) * 32;
    if (writer) cand[ph + entry] = w;
    __syncthreads();                     // the ONLY barrier per step
    // each lane reads one pair of the 32 row-winners (broadcast, 2-way banks)
    double2 pr = ((const double2*)(cand + ph))[t & 15];
    double w2 = rowmax16(dmax(pr.x, pr.y));
    const int sel = 4095 - pk_lo(w2);
    const float sx = lx[sel], sy = ly[sel], sz = lz[sel];  // broadcast reads
    if (t == 0) csel[s] = sel;
    // distance update + fresh per-thread best
    double k4[4];
    #pragma unroll
    for (int jp = 0; jp < 4; ++jp) {
      const int j0 = 2*jp, j1 = 2*jp + 1;
      float dx0 = px[j0]-sx, dy0 = py[j0]-sy, dz0 = pz[j0]-sz;
      float dx1 = px[j1]-sx, dy1 = py[j1]-sy, dz1 = pz[j1]-sz;
      float d0 = (dx0*dx0 + dy0*dy0) + dz0*dz0;
      float d1 = (dx1*dx1 + dy1*dy1) + dz1*dz1;
      float m0 = fminf(mind[j0], d0), m1 = fminf(mind[j1], d1);
      mind[j0] = m0; mind[j1] = m1;
      k4[jp] = dmax(pk(m0, lo8[j0]), pk(m1, lo8[j1]));
    }
    bk = dmax(dmax(k4[0], k4[1]), dmax(k4[2], k4[3]));
  }
  __syncthreads();
  // coalesced output pass (coords re-read from LDS by selected index)
  for (int c = t; c < MPC; c += 512) {
    const int il = csel[c];
    const int cl = b*MPC + c;
    const float X = lx[il], Y = ly[il], Z = lz[il];
    centers[cl] = make_float4(X, Y, Z, 0.0f);
    out[OFF_SUBPOS + cl*3 + 0] = X;
    out[OFF_SUBPOS + cl*3 + 1] = Y;
    out[OFF_SUBPOS + cl*3 + 2] = Z;
    out[OFF_SUBB + cl] = (float)b;
    out[OFF_IDCL + cl] = (float)(b*NPC + il);
  }
}

// ---------------- GEMM block (512 thr): h = x@W + b, plus BN sum/sumsq ------
__device__ void gemm_block(char* smem, const float* __restrict__ x,
                           const float* __restrict__ W, const float* __restrict__ bias,
                           float* __restrict__ h, float* __restrict__ stats, int blk)
{
  float (*xT)[68]  = (float(*)[68])(smem + SM_XT);   // [k][row], padded
  float (*Wl)[128] = (float(*)[128])(smem + SM_WL);
  float* bsum = (float*)(smem + SM_BS);
  float* bsq  = (float*)(smem + SM_BQ);
  const int t = threadIdx.x;
  const int row0 = blk * 64;
  if (t < 128) { bsum[t] = 0.0f; bsq[t] = 0.0f; }
  #pragma unroll
  for (int i = 0; i < 8; ++i) {
    const int idx = t + i*512;
    xT[idx & 63][idx >> 6] = x[(size_t)row0*64 + idx];
  }
  #pragma unroll
  for (int i = 0; i < 16; ++i) {
    const int idx = t + i*512;
    ((float*)Wl)[idx] = W[idx];
  }
  __syncthreads();
  const int tx = t & 31, ty = t >> 5;   // 32x16 threads, 4 rows x 4 cols each
  float acc[4][4] = {};
  #pragma unroll 8
  for (int k = 0; k < 64; ++k) {
    const float4 a  = *(const float4*)&xT[k][ty*4];
    const float4 b0 = *(const float4*)&Wl[k][tx*4];
    const float av[4] = {a.x, a.y, a.z, a.w};
    const float bw[4] = {b0.x, b0.y, b0.z, b0.w};
    #pragma unroll
    for (int i2 = 0; i2 < 4; ++i2)
      #pragma unroll
      for (int e = 0; e < 4; ++e)
        acc[i2][e] += av[i2] * bw[e];
  }
  const int c0 = tx*4;
  float bb[4];
  #pragma unroll
  for (int e = 0; e < 4; ++e) bb[e] = bias[c0+e];
  float s4[4] = {}, q4[4] = {};
  #pragma unroll
  for (int i2 = 0; i2 < 4; ++i2) {
    float vv[4];
    #pragma unroll
    for (int e = 0; e < 4; ++e) {
      float v = acc[i2][e] + bb[e];
      vv[e] = v; s4[e] += v; q4[e] += v*v;
    }
    const int r = row0 + ty*4 + i2;
    *(float4*)&h[(size_t)r*128 + c0] = make_float4(vv[0], vv[1], vv[2], vv[3]);
  }
  #pragma unroll
  for (int e = 0; e < 4; ++e) {
    atomicAdd(&bsum[c0+e], s4[e]);
    atomicAdd(&bsq[c0+e],  q4[e]);
  }
  __syncthreads();
  if (t < 128) {
    atomicAdd(&stats[t],      bsum[t]);
    atomicAdd(&stats[128+t],  bsq[t]);
  }
}

// ---------------- fused launcher kernel -------------------------------------
__global__ __launch_bounds__(512) void fused_fps_gemm(const float* __restrict__ pos,
                                                      float4* __restrict__ centers,
                                                      float* __restrict__ out,
                                                      const float* __restrict__ x,
                                                      const float* __restrict__ W,
                                                      const float* __restrict__ bias,
                                                      float* __restrict__ h,
                                                      float* __restrict__ stats)
{
  __shared__ __align__(16) char smem[SM_SIZE];
  if (blockIdx.x < NB) fps_block(smem, pos, centers, out);
  else                 gemm_block(smem, x, W, bias, h, stats, blockIdx.x - NB);
}

// ------- kNN + BN + pool fused: 512 blocks, 32 centers each -----------------
// kNN keys: f64 pack (d2 bits, idx); MIN key == lex (d2 asc, idx asc).
// Per-lane sorted-descending list L[0..15] (L[0] = worst): insert is 31 f64
// min/max ops, no rescan.
#define KBIG __hiloint2double(0x7f7fffff, 0xffffffff)
#define CD_STRIDE 17                     // pad: kill 32-way write conflicts

__global__ __launch_bounds__(256) void knn_pool(const float* __restrict__ pos,
                                                const float4* __restrict__ centers,
                                                const float* __restrict__ h,
                                                const float* __restrict__ aux,
                                                const float* __restrict__ stats,
                                                const float* __restrict__ gamma,
                                                const float* __restrict__ beta,
                                                float* __restrict__ out)
{
  #pragma clang fp contract(off)
  __shared__ float4 lp[NPC];        // 64KB; reused as candidate scratch after scan
  __shared__ float  scl[128], ssh[128];
  __shared__ int    fid[32][16];
  const int blk = blockIdx.x;       // 512 blocks; 32 per cloud
  const int b   = blk >> 5;
  const int c0  = (blk & 31) * 32;  // first local center of this block
  const int t   = threadIdx.x;
  const int q   = t & 7;            // subset
  const int cc  = t >> 3;           // center within block, 0..31
  // BN scale/shift (redundant per block; trivial)
  if (t < 128) {
    const float inv = 1.0f / 65536.0f;
    const float mu  = stats[t] * inv;
    const float var = stats[128+t] * inv - mu*mu;
    const float sc  = gamma[t] * rsqrtf(var + 1e-5f);
    scl[t] = sc;
    ssh[t] = beta[t] - mu*sc;
  }
  const float* pb = pos + (size_t)b * NPC * 3;
  for (int i = t; i < NPC; i += 256)
    lp[i] = make_float4(pb[3*i], pb[3*i+1], pb[3*i+2], 0.0f);
  __syncthreads();
  const int cg = b*MPC + c0 + cc;   // global cluster index
  const float4 C = centers[cg];
  double L[16];
  #pragma unroll
  for (int k = 0; k < 16; ++k) L[k] = KBIG;
  for (int jj = 0; jj < NPC/8; ++jj) {
    const int j = jj*8 + q;
    const float4 p = lp[j];
    float dx = C.x - p.x, dy = C.y - p.y, dz = C.z - p.z;
    float d2 = (dx*dx + dy*dy) + dz*dz;   // no-FMA
    double nk = pk(d2, j);
    if (nk < L[0]) {                      // beats current worst -> sorted insert
      #pragma unroll
      for (int k = 0; k < 15; ++k) L[k] = dmin(L[k], dmax(L[k+1], nk));
      L[15] = dmin(L[15], nk);
    }
  }
  __syncthreads();                  // pos data no longer needed
  double* cd = (double*)lp;         // [256 lanes][17-padded 16 keys] = 34816 B
  #pragma unroll
  for (int k = 0; k < 16; ++k) cd[t*CD_STRIDE + k] = L[k];
  __syncthreads();
  if (q == 0) {
    // merge 8 sorted sublists (128 keys) -> exact global top-16 set
    double M[16];
    #pragma unroll
    for (int k = 0; k < 16; ++k) M[k] = KBIG;
    for (int ss = 0; ss < 8; ++ss) {
      const double* src = cd + (cc*8 + ss)*CD_STRIDE;
      #pragma unroll
      for (int k = 0; k < 16; ++k) {
        double nk = src[k];
        if (nk < M[0]) {
          #pragma unroll
          for (int m = 0; m < 15; ++m) M[m] = dmin(M[m], dmax(M[m+1], nk));
          M[15] = dmin(M[15], nk);
        }
      }
    }
    #pragma unroll
    for (int k = 0; k < 16; ++k) fid[cc][k] = b*NPC + pk_lo(M[k]);
  }
  __syncthreads();
  // ---- pool: 16 passes, 2 clusters per pass (128 cols each) ----------------
  for (int g = 0; g < 16; ++g) {
    const int cc2 = g*2 + (t >> 7);        // 0..31
    const int col = t & 127;
    const int cl  = b*MPC + c0 + cc2;
    const float sc = scl[col], sh = ssh[col];
    float mv = 0.0f;                       // relu >= 0, so 0 == -inf here
    #pragma unroll
    for (int k = 0; k < 16; ++k) {
      const float hv = h[(size_t)fid[cc2][k]*128 + col];
      mv = fmaxf(mv, fmaxf(sc*hv + sh, 0.0f));
    }
    out[OFF_XOUT + (size_t)cl*128 + col] = mv;
    if (col < 32) {
      float s = 0.0f;
      #pragma unroll
      for (int k = 0; k < 16; ++k) s += aux[(size_t)fid[cc2][k]*32 + col];
      out[OFF_AUX + (size_t)cl*32 + col] = s * (1.0f/16.0f);
    }
  }
}

extern "C" void kernel_launch(void* const* d_in, const int* in_sizes, int n_in,
                              void* d_out, int out_size, void* d_ws, size_t ws_size,
                              hipStream_t stream)
{
  const float* x     = (const float*)d_in[0];
  const float* pos   = (const float*)d_in[1];
  // d_in[2] = batch (int32) — clouds are equal-size, derived analytically
  const float* aux   = (const float*)d_in[3];
  const float* W     = (const float*)d_in[4];
  const float* bias  = (const float*)d_in[5];
  const float* gamma = (const float*)d_in[6];
  const float* beta  = (const float*)d_in[7];
  float* out = (float*)d_out;
  char*  ws  = (char*)d_ws;
  if (ws_size < (size_t)WS_NEED) return;   // insufficient scratch: bail cleanly

  float*  h       = (float*)(ws + WS_H);
  float4* centers = (float4*)(ws + WS_CENTERS);
  float*  stats   = (float*)(ws + WS_STATS);

  hipMemsetAsync(stats, 0, 256*4, stream);  // BN accumulators: zero every call
  hipLaunchKernelGGL(fused_fps_gemm, dim3(NB + PTOT/64), dim3(512), 0, stream,
                     pos, centers, out, x, W, bias, h, stats);
  hipLaunchKernelGGL(knn_pool, dim3(512), dim3(256), 0, stream,
                     pos, centers, h, aux, stats, gamma, beta, out);
}